// Round 5
// baseline (679.753 us; speedup 1.0000x reference)
//
#include <hip/hip_runtime.h>
#include <cstdint>
#include <cstddef>

#define MEAN_C 0.1307f
#define SIGMA_C 0.3081f
#define SIG_SCALE_C 5.0f

typedef __bf16 bf16_t;
typedef __bf16 bf16x8 __attribute__((ext_vector_type(8)));
typedef __bf16 bf16x4 __attribute__((ext_vector_type(4)));
typedef float f32x4 __attribute__((ext_vector_type(4)));

__device__ __forceinline__ f32x4 mfma16(bf16x8 a, bf16x8 b, f32x4 c) {
    return __builtin_amdgcn_mfma_f32_16x16x32_bf16(a, b, c, 0, 0, 0);
}

typedef const __attribute__((address_space(1))) void* gvp;
typedef __attribute__((address_space(3))) void* lvp;
__device__ __forceinline__ void g2l16(const void* g, void* l) {
    __builtin_amdgcn_global_load_lds((gvp)g, (lvp)l, 16, 0, 0);
}

// swizzled bf16 operand layout: 16x32 tiles (1KB); chunk index within tile =
// lane = (k-chunk)*16 + row  (16B each). offset(r,k), K = ktiles*32.
__device__ __forceinline__ size_t swz(int r, int k, int ktiles) {
    return (((size_t)(r >> 4) * ktiles + (k >> 5)) << 9)
         + (((k >> 3) & 3) << 7) + ((r & 15) << 3) + (k & 7);
}

#define KTILES 64   // K = 2048

// ---------------- device helpers ----------------

__device__ __forceinline__ float sigmoidf_(float x) {
    if (x >= 0.f) { float e = __expf(-x); return 1.f / (1.f + e); }
    float e = __expf(x); return e / (1.f + e);
}

__device__ __forceinline__ float spu_f(float x) {
    return (x >= 0.f) ? (x * x - 0.5f) : (sigmoidf_(-x) - 1.f);
}

__device__ __forceinline__ float wave_sum(float a) {
    #pragma unroll
    for (int o = 32; o > 0; o >>= 1) a += __shfl_xor(a, o, 64);
    return a;
}

// ---------------- small kernels ----------------

__global__ void k_input_bounds(const float* __restrict__ x, const float* __restrict__ eps,
                               int n, float* __restrict__ ubn, float* __restrict__ lbn) {
    int i = blockIdx.x * blockDim.x + threadIdx.x;
    if (i >= n) return;
    float e = eps[0];
    float ub = fminf(x[i] + e, 1.f);
    float lb = fmaxf(x[i] - e, 0.f);
    ubn[i] = (ub - MEAN_C) / SIGMA_C;
    lbn[i] = (lb - MEAN_C) / SIGMA_C;
}

// wave-per-row interval bound
__global__ __launch_bounds__(256) void k_interval_affine(
        const float* __restrict__ W, const float* __restrict__ b,
        const float* __restrict__ U, const float* __restrict__ L,
        int m, int nrows, float* __restrict__ uo, float* __restrict__ lo) {
    int r = (blockIdx.x << 2) + (threadIdx.x >> 6);
    if (r >= nrows) return;
    int lane = threadIdx.x & 63;
    const f32x4* Wr = (const f32x4*)(W + (size_t)r * m);
    const f32x4* U4 = (const f32x4*)U;
    const f32x4* L4 = (const f32x4*)L;
    int nf4 = m >> 2;
    float au = 0.f, al = 0.f;
    for (int j = lane; j < nf4; j += 64) {
        f32x4 wv = Wr[j], uu = U4[j], ll = L4[j];
        #pragma unroll
        for (int u = 0; u < 4; ++u) {
            float w = wv[u];
            float hi = (w > 0.f) ? uu[u] : ll[u];
            float lo2 = (w > 0.f) ? ll[u] : uu[u];
            au = fmaf(w, hi, au);
            al = fmaf(w, lo2, al);
        }
    }
    au = wave_sum(au); al = wave_sum(al);
    if (lane == 0) { uo[r] = au + b[r]; lo[r] = al + b[r]; }
}

__global__ void k_spu(const float* __restrict__ Uin, const float* __restrict__ Lin, int n,
                      float* __restrict__ us, float* __restrict__ ui,
                      float* __restrict__ ls, float* __restrict__ li,
                      float* __restrict__ nu, float* __restrict__ nl) {
    int i = blockIdx.x * blockDim.x + threadIdx.x;
    if (i >= n) return;
    float ux = Uin[i], lx = Lin[i];
    float uy = spu_f(ux), ly = spu_f(lx);
    float new_ub = fmaxf(uy, ly);
    float sj = (uy - ly) / (ux - lx);
    float ij = uy - sj * ux;
    bool right = lx > 0.f;
    bool left = ux <= 0.f;
    bool crossing = (!left) && (!right);
    float mid = 0.5f * (ux + lx);
    float sp = 2.f * mid, ip = -mid * mid - 0.5f;
    float sm = sigmoidf_(mid);
    float ssm = -sm * (1.f - sm);
    float ism = -sm - ssm * mid;
    float new_lb = crossing ? -0.5f : fminf(uy, ly);
    float spu_s = 2.f * ux, ipu = -ux * ux - 0.5f;
    float limit = spu_s * lx + ipu;
    float clm = (fabsf(lx) > ux) ? 1.f : 0.f;
    float clp = sigmoidf_((clm - 0.5f) * 2.f * SIG_SCALE_C) * (ly - limit) + limit;
    bool ptm = clp < -0.5f;
    float D = 4.f * lx * lx - 4.f * clp - 2.f;
    float x2 = (2.f * lx + sqrtf(fmaxf(D, 0.f))) * 0.5f;
    float spt = 2.f * x2, ipt = -x2 * x2 - 0.5f;
    float sjn = (clp + 0.5f) / lx;
    float ijn = -0.5f;
    float s_cl = ptm ? spt : sjn;
    float i_cl = ptm ? ipt : ijn;
    float sl = sigmoidf_(lx);
    float ssl = -sl * (1.f - sl);
    float isl = -sl - ssl * lx;
    float stv = ssl * ux + isl - uy;
    float Lb = lx, Rb = 0.f;
    #pragma unroll
    for (int t = 0; t < 10; ++t) {
        float mm = 0.5f * (Lb + Rb);
        float smm = sigmoidf_(mm);
        float sms = -smm * (1.f - smm);
        float smi = -smm - sms * mm;
        bool mask = (sms * ux + smi - uy) > 0.f;
        Lb = mask ? mm : Lb;
        Rb = mask ? Rb : mm;
    }
    float scp = sigmoidf_(-SIG_SCALE_C) * (Lb - lx) + lx;
    float sc = sigmoidf_(scp);
    float ssc = -sc * (1.f - sc);
    float isc = -sc - ssc * scp;
    bool up = stv > 0.f;
    float s_cu = up ? ssc : sj;
    float i_cu = up ? isc : ij;
    float usv, uiv, lsv, liv;
    if (right)      { usv = sj;   uiv = ij;   lsv = sp;   liv = ip;   }
    else if (left)  { usv = ssm;  uiv = ism;  lsv = sj;   liv = ij;   }
    else            { usv = s_cu; uiv = i_cu; lsv = s_cl; liv = i_cl; }
    us[i] = usv; ui[i] = uiv; ls[i] = lsv; li[i] = liv;
    nu[i] = new_ub; nl[i] = new_lb;
}

// layer-1 fused backsub (fp32 exact, no intermediate matrix)
__global__ __launch_bounds__(256) void k_bsub1(
        const float* __restrict__ W, const float* __restrict__ b, int n, int m,
        const float* __restrict__ rsU, const float* __restrict__ riU,
        const float* __restrict__ rsL, const float* __restrict__ riL,
        const float* __restrict__ ubn, const float* __restrict__ lbn,
        float* __restrict__ U, float* __restrict__ L) {
    int r = (blockIdx.x << 2) + (threadIdx.x >> 6);
    if (r >= 2 * n) return;
    int lane = threadIdx.x & 63;
    bool isU = r < n;
    int i = isU ? r : r - n;
    float rs = isU ? rsU[i] : rsL[i];
    float ri = isU ? riU[i] : riL[i];
    const f32x4* Wr = (const f32x4*)(W + (size_t)i * m);
    const f32x4* P = (const f32x4*)(isU ? ubn : lbn);
    const f32x4* Q = (const f32x4*)(isU ? lbn : ubn);
    int nf4 = m >> 2;
    float a = 0.f;
    for (int j = lane; j < nf4; j += 64) {
        f32x4 wv = Wr[j], pp = P[j], qq = Q[j];
        #pragma unroll
        for (int u = 0; u < 4; ++u) {
            float w = rs * wv[u];
            a += fmaxf(w, 0.f) * pp[u] + fminf(w, 0.f) * qq[u];
        }
    }
    a = wave_sum(a);
    if (lane == 0) {
        float v = a + rs * b[i] + ri;
        if (isU) U[i] = fminf(U[i], v);
        else     L[i] = fmaxf(L[i], v);
    }
}

// ---------------- bf16 producers ----------------

// transpose + convert + swizzle: W (K x N real, ldw) fp32 -> Wt swizzled (Npad x K)
__global__ __launch_bounds__(256) void k_wT(
        const float* __restrict__ W, int N, int ldw,
        bf16_t* __restrict__ Wt) {
    __shared__ bf16_t t[64][72];
    int k0 = blockIdx.x * 64, n0 = blockIdx.y * 64;
    int tid = threadIdx.x;
    int r = tid >> 2;
    int c0 = (tid & 3) * 16;
    const float* Wr = W + (size_t)(k0 + r) * ldw;
    #pragma unroll
    for (int c = 0; c < 16; ++c) {
        int gn = n0 + c0 + c;
        float vv = (gn < N) ? Wr[gn] : 0.f;
        t[c0 + c][r] = (bf16_t)vv;
    }
    __syncthreads();
    #pragma unroll
    for (int p = 0; p < 2; ++p) {
        int c = tid + p * 256;
        int lr = c & 63, lq = c >> 6;
        bf16x8 v;
        #pragma unroll
        for (int u = 0; u < 8; ++u) v[u] = t[lr][lq * 8 + u];
        *(bf16x8*)(Wt + swz(n0 + lr, k0 + lq * 8, KTILES)) = v;
    }
}

// prep: one 16-row tile per block; lane owns chunk lane of each k-tile.
__global__ __launch_bounds__(256) void k_prep16(
        const float* __restrict__ W, const float* __restrict__ b, int n,
        const float* __restrict__ rsU, const float* __restrict__ riU,
        const float* __restrict__ rsL, const float* __restrict__ riL,
        const float* __restrict__ cus, const float* __restrict__ cui,
        const float* __restrict__ cls, const float* __restrict__ cli,
        const float* __restrict__ bvec,
        bf16_t* __restrict__ Ab, float* __restrict__ av) {
    int rt = blockIdx.x;
    int tid = threadIdx.x, lane = tid & 63, wid = tid >> 6;
    int mrow = lane & 15, q = lane >> 4;
    int r = rt * 16 + mrow;
    bool act = r < 2 * n;
    bool isU = r < n;
    int i = act ? (isU ? r : r - n) : 0;
    float rs = 1.f;
    if (rsU) rs = isU ? rsU[i] : rsL[i];
    if (!act) rs = 0.f;
    const float* Wr = W + (size_t)i * 2048;
    const float* ps = isU ? cus : cls;
    const float* ns = isU ? cls : cus;
    const float* yi = isU ? cui : cli;
    const float* zi = isU ? cli : cui;
    float a = 0.f;
    bf16_t* Abase = Ab + ((size_t)rt * KTILES) * 512 + lane * 8;
    for (int kt = wid; kt < KTILES; kt += 4) {
        int k0 = kt * 32 + q * 8;
        f32x4 w0 = *(const f32x4*)(Wr + k0);
        f32x4 w1 = *(const f32x4*)(Wr + k0 + 4);
        f32x4 p0 = *(const f32x4*)(ps + k0), p1 = *(const f32x4*)(ps + k0 + 4);
        f32x4 q0 = *(const f32x4*)(ns + k0), q1 = *(const f32x4*)(ns + k0 + 4);
        f32x4 y0 = *(const f32x4*)(yi + k0), y1 = *(const f32x4*)(yi + k0 + 4);
        f32x4 z0 = *(const f32x4*)(zi + k0), z1 = *(const f32x4*)(zi + k0 + 4);
        f32x4 c0 = *(const f32x4*)(bvec + k0), c1 = *(const f32x4*)(bvec + k0 + 4);
        bf16x8 ov;
        #pragma unroll
        for (int u = 0; u < 4; ++u) {
            float w = rs * w0[u];
            float pos = fmaxf(w, 0.f), neg = fminf(w, 0.f);
            float mx = pos * p0[u] + neg * q0[u];
            ov[u] = (bf16_t)mx;
            a += pos * y0[u] + neg * z0[u] + mx * c0[u];
        }
        #pragma unroll
        for (int u = 0; u < 4; ++u) {
            float w = rs * w1[u];
            float pos = fmaxf(w, 0.f), neg = fminf(w, 0.f);
            float mx = pos * p1[u] + neg * q1[u];
            ov[4 + u] = (bf16_t)mx;
            a += pos * y1[u] + neg * z1[u] + mx * c1[u];
        }
        *(bf16x8*)(Abase + (size_t)kt * 512) = ov;
    }
    a += __shfl_xor(a, 16, 64);
    a += __shfl_xor(a, 32, 64);
    __shared__ float sh[4][16];
    if (lane < 16) sh[wid][lane] = a;
    __syncthreads();
    if (tid < 16) {
        int r2 = rt * 16 + tid;
        float tot = sh[0][tid] + sh[1][tid] + sh[2][tid] + sh[3][tid];
        if (r2 < 2 * n) {
            bool isU2 = r2 < n;
            int i2 = isU2 ? r2 : r2 - n;
            float rs2 = 1.f, ri2 = 0.f;
            if (rsU) { rs2 = isU2 ? rsU[i2] : rsL[i2]; ri2 = isU2 ? riU[i2] : riL[i2]; }
            av[r2] = tot + rs2 * b[i2] + ri2;
        } else {
            av[r2] = 0.f;
        }
    }
}

// colmix: bf16 split slabs summed in fp32 -> swizzled bf16 Ab; av += dots (atomic)
__global__ __launch_bounds__(256) void k_colmix16(
        const bf16_t* __restrict__ Cb, int ldc, int splits, size_t sstride, int n,
        int tpb,
        const float* __restrict__ cus, const float* __restrict__ cui,
        const float* __restrict__ cls, const float* __restrict__ cli,
        const float* __restrict__ bvec,
        bf16_t* __restrict__ Ab, float* __restrict__ av) {
    int rt = blockIdx.x;
    int kt0 = blockIdx.y * tpb;
    int tid = threadIdx.x, lane = tid & 63, wid = tid >> 6;
    int mrow = lane & 15, q = lane >> 4;
    int r = rt * 16 + mrow;
    bool isU = r < n;
    const bf16_t* Cr = Cb + (size_t)r * ldc;
    const float* ps = isU ? cus : cls;
    const float* ns = isU ? cls : cus;
    const float* yi = isU ? cui : cli;
    const float* zi = isU ? cli : cui;
    float a = 0.f;
    bf16_t* Abase = Ab + ((size_t)rt * KTILES) * 512 + lane * 8;
    for (int kt = kt0 + wid; kt < kt0 + tpb; kt += 4) {
        int k0 = kt * 32 + q * 8;
        float wsum[8] = {0.f, 0.f, 0.f, 0.f, 0.f, 0.f, 0.f, 0.f};
        for (int s = 0; s < splits; ++s) {
            bf16x8 v = *(const bf16x8*)(Cr + s * sstride + k0);
            #pragma unroll
            for (int u = 0; u < 8; ++u) wsum[u] += (float)v[u];
        }
        f32x4 p0 = *(const f32x4*)(ps + k0), p1 = *(const f32x4*)(ps + k0 + 4);
        f32x4 q0 = *(const f32x4*)(ns + k0), q1 = *(const f32x4*)(ns + k0 + 4);
        f32x4 y0 = *(const f32x4*)(yi + k0), y1 = *(const f32x4*)(yi + k0 + 4);
        f32x4 z0 = *(const f32x4*)(zi + k0), z1 = *(const f32x4*)(zi + k0 + 4);
        f32x4 c0 = *(const f32x4*)(bvec + k0), c1 = *(const f32x4*)(bvec + k0 + 4);
        bf16x8 ov;
        #pragma unroll
        for (int u = 0; u < 4; ++u) {
            float w = wsum[u];
            float pos = fmaxf(w, 0.f), neg = fminf(w, 0.f);
            float mx = pos * p0[u] + neg * q0[u];
            ov[u] = (bf16_t)mx;
            a += pos * y0[u] + neg * z0[u] + mx * c0[u];
        }
        #pragma unroll
        for (int u = 0; u < 4; ++u) {
            float w = wsum[4 + u];
            float pos = fmaxf(w, 0.f), neg = fminf(w, 0.f);
            float mx = pos * p1[u] + neg * q1[u];
            ov[4 + u] = (bf16_t)mx;
            a += pos * y1[u] + neg * z1[u] + mx * c1[u];
        }
        *(bf16x8*)(Abase + (size_t)kt * 512) = ov;
    }
    a += __shfl_xor(a, 16, 64);
    a += __shfl_xor(a, 32, 64);
    __shared__ float sh[4][16];
    if (lane < 16) sh[wid][lane] = a;
    __syncthreads();
    if (tid < 16) {
        float tot = sh[0][tid] + sh[1][tid] + sh[2][tid] + sh[3][tid];
        atomicAdd(&av[rt * 16 + tid], tot);
    }
}

// final c0 step: bf16 slabs summed + av -> U=min(U,v) / L=max(L,v)
__global__ __launch_bounds__(256) void k_reduce16(
        const bf16_t* __restrict__ Cb, int ldc, int m, int n,
        int splits, size_t sstride,
        const float* __restrict__ av,
        const float* __restrict__ ubn, const float* __restrict__ lbn,
        float* __restrict__ U, float* __restrict__ L) {
    int r = (blockIdx.x << 2) + (threadIdx.x >> 6);
    if (r >= 2 * n) return;
    int lane = threadIdx.x & 63;
    bool isU = r < n;
    int i = isU ? r : r - n;
    const bf16_t* Cr = Cb + (size_t)r * ldc;
    const float* p = isU ? ubn : lbn;
    const float* q = isU ? lbn : ubn;
    int nch = m >> 3;   // m % 8 == 0
    float a = 0.f;
    for (int c = lane; c < nch; c += 64) {
        float wsum[8] = {0.f, 0.f, 0.f, 0.f, 0.f, 0.f, 0.f, 0.f};
        for (int s = 0; s < splits; ++s) {
            bf16x8 v = *(const bf16x8*)(Cr + s * sstride + c * 8);
            #pragma unroll
            for (int u = 0; u < 8; ++u) wsum[u] += (float)v[u];
        }
        f32x4 p0 = *(const f32x4*)(p + c * 8), p1 = *(const f32x4*)(p + c * 8 + 4);
        f32x4 q0 = *(const f32x4*)(q + c * 8), q1 = *(const f32x4*)(q + c * 8 + 4);
        #pragma unroll
        for (int u = 0; u < 4; ++u) {
            a += fmaxf(wsum[u], 0.f) * p0[u] + fminf(wsum[u], 0.f) * q0[u];
            a += fmaxf(wsum[4 + u], 0.f) * p1[u] + fminf(wsum[4 + u], 0.f) * q1[u];
        }
    }
    a = wave_sum(a);
    if (lane == 0) {
        float v = a + av[r];
        if (isU) U[i] = fminf(U[i], v);
        else     L[i] = fmaxf(L[i], v);
    }
}

__global__ void k_final_min(const float* __restrict__ l, int n, float* __restrict__ out) {
    float v = 3.4e38f;
    for (int j = threadIdx.x; j < n; j += 64) v = fminf(v, l[j]);
    #pragma unroll
    for (int o = 32; o > 0; o >>= 1) v = fminf(v, __shfl_down(v, o, 64));
    if (threadIdx.x == 0) out[0] = v;
}

// ---------------- bf16 MFMA GEMM, global_load_lds staging, bf16 slab output ----
// Operand-swapped MFMA: D-layout transposed so each lane holds 4 consecutive
// cols of one row -> packed bf16x4 (8B) epilogue stores.
__global__ __launch_bounds__(256) void k_gemm16(
        const bf16_t* __restrict__ A, const bf16_t* __restrict__ Bt,
        bf16_t* __restrict__ C, int ldc, size_t sstride, int nk) {
    __shared__ __align__(16) bf16_t As[4096];
    __shared__ __align__(16) bf16_t Bs[4096];
    int tid = threadIdx.x, lane = tid & 63, w = tid >> 6;
    int wm = w & 1, wn = w >> 1;
    int tr0 = blockIdx.y * 8, tc0 = blockIdx.x * 8;
    int kt0 = blockIdx.z * nk;

    const bf16_t* a0 = A + (((size_t)(tr0 + w)     * KTILES + kt0) << 9) + lane * 8;
    const bf16_t* a1 = A + (((size_t)(tr0 + w + 4) * KTILES + kt0) << 9) + lane * 8;
    const bf16_t* b0 = Bt + (((size_t)(tc0 + w)     * KTILES + kt0) << 9) + lane * 8;
    const bf16_t* b1 = Bt + (((size_t)(tc0 + w + 4) * KTILES + kt0) << 9) + lane * 8;
    bf16_t* lA0 = &As[w * 512];
    bf16_t* lA1 = &As[(w + 4) * 512];
    bf16_t* lB0 = &Bs[w * 512];
    bf16_t* lB1 = &Bs[(w + 4) * 512];

    f32x4 acc[4][4];
    #pragma unroll
    for (int i = 0; i < 4; ++i)
        #pragma unroll
        for (int j = 0; j < 4; ++j) acc[i][j] = (f32x4){0.f, 0.f, 0.f, 0.f};

    for (int kk = 0; kk < nk; ++kk) {
        g2l16(a0 + (size_t)kk * 512, lA0);
        g2l16(a1 + (size_t)kk * 512, lA1);
        g2l16(b0 + (size_t)kk * 512, lB0);
        g2l16(b1 + (size_t)kk * 512, lB1);
        __syncthreads();
        bf16x8 af[4], bfr[4];
        #pragma unroll
        for (int i = 0; i < 4; ++i)
            af[i] = *(const bf16x8*)(&As[(wm * 4 + i) * 512 + lane * 8]);
        #pragma unroll
        for (int j = 0; j < 4; ++j)
            bfr[j] = *(const bf16x8*)(&Bs[(wn * 4 + j) * 512 + lane * 8]);
        #pragma unroll
        for (int i = 0; i < 4; ++i)
            #pragma unroll
            for (int j = 0; j < 4; ++j)
                acc[i][j] = mfma16(bfr[j], af[i], acc[i][j]);   // swapped -> D^T layout
        __syncthreads();
    }
    // swapped D layout: out row = lane&15 (+16*i block), out cols = (lane>>4)*4 + rg
    bf16_t* Cz = C + (size_t)blockIdx.z * sstride;
    int orow = lane & 15, ocol = (lane >> 4) * 4;
    size_t row0 = (size_t)blockIdx.y * 128;
    size_t col0 = (size_t)blockIdx.x * 128;
    #pragma unroll
    for (int i = 0; i < 4; ++i) {
        size_t gr = row0 + wm * 64 + i * 16 + orow;
        #pragma unroll
        for (int j = 0; j < 4; ++j) {
            size_t gc = col0 + wn * 64 + j * 16 + ocol;
            bf16x4 v;
            #pragma unroll
            for (int rg = 0; rg < 4; ++rg) v[rg] = (bf16_t)acc[i][j][rg];
            *(bf16x4*)(Cz + gr * (size_t)ldc + gc) = v;
        }
    }
}

// ---------------- host launch ----------------

extern "C" void kernel_launch(void* const* d_in, const int* in_sizes, int n_in,
                              void* d_out, int out_size, void* d_ws, size_t ws_size,
                              hipStream_t stream) {
    (void)in_sizes; (void)n_in; (void)out_size; (void)ws_size;
    const float* x   = (const float*)d_in[0];
    const float* eps = (const float*)d_in[1];
    const float* W1  = (const float*)d_in[2];
    const float* B1  = (const float*)d_in[3];
    const float* W2  = (const float*)d_in[4];
    const float* B2  = (const float*)d_in[5];
    const float* W3  = (const float*)d_in[6];
    const float* B3  = (const float*)d_in[7];
    const float* W4  = (const float*)d_in[8];
    const float* B4  = (const float*)d_in[9];
    float* out = (float*)d_out;

    const int H = 2048, DIN = 784, DOUT = 10;
    const int NP1 = 896;           // DIN padded to x128
    const int MP4 = 128;           // layer-4 row pad

    float* ws = (float*)d_ws;
    size_t off = 0;
    auto alloc = [&](size_t nf) -> float* {
        float* p = ws + off;
        off += (nf + 3) & ~(size_t)3;
        return p;
    };
    float* ubn = alloc(DIN);
    float* lbn = alloc(DIN);
    float* bU1 = alloc(H); float* bL1 = alloc(H);
    float* us1 = alloc(H); float* ui1 = alloc(H); float* ls1 = alloc(H); float* li1 = alloc(H);
    float* pU1 = alloc(H); float* pL1 = alloc(H);
    float* bU2 = alloc(H); float* bL2 = alloc(H);
    float* us2 = alloc(H); float* ui2 = alloc(H); float* ls2 = alloc(H); float* li2 = alloc(H);
    float* pU2 = alloc(H); float* pL2 = alloc(H);
    float* bU3 = alloc(H); float* bL3 = alloc(H);
    float* us3 = alloc(H); float* ui3 = alloc(H); float* ls3 = alloc(H); float* li3 = alloc(H);
    float* pU3 = alloc(H); float* pL3 = alloc(H);
    float* bU4 = alloc(32); float* bL4 = alloc(32);
    float* av  = alloc(2 * H);
    bf16_t* Ab  = (bf16_t*)alloc((size_t)2 * H * H / 2);       // 4096 x 2048 bf16 swz
    bf16_t* W1t = (bf16_t*)alloc((size_t)NP1 * H / 2);
    bf16_t* W2t = (bf16_t*)alloc((size_t)H * H / 2);
    bf16_t* W3t = (bf16_t*)alloc((size_t)H * H / 2);
    bf16_t* Cs  = (bf16_t*)alloc((size_t)2 * H * H);           // bf16 slab space (33.5 MB max)

    dim3 blk(256);
    auto gemm = [&](const bf16_t* A, const bf16_t* Bt, bf16_t* C, int N, int Mpad, int splits) {
        dim3 g(N / 128, Mpad / 128, splits);
        k_gemm16<<<g, blk, 0, stream>>>(A, Bt, C, N, (size_t)Mpad * N, KTILES / splits);
    };

    // weight transpose/convert/swizzle
    k_wT<<<dim3(H / 64, NP1 / 64), blk, 0, stream>>>(W1, DIN, DIN, W1t);
    k_wT<<<dim3(H / 64, H / 64), blk, 0, stream>>>(W2, H, H, W2t);
    k_wT<<<dim3(H / 64, H / 64), blk, 0, stream>>>(W3, H, H, W3t);

    k_input_bounds<<<dim3((DIN + 255) / 256), blk, 0, stream>>>(x, eps, DIN, ubn, lbn);

    // ======== Layer 1 (fp32 exact) ========
    k_interval_affine<<<dim3(H / 4), blk, 0, stream>>>(W1, B1, ubn, lbn, DIN, H, bU1, bL1);
    k_spu<<<dim3(H / 256), blk, 0, stream>>>(bU1, bL1, H, us1, ui1, ls1, li1, pU1, pL1);
    k_bsub1<<<dim3(2 * H / 4), blk, 0, stream>>>(W1, B1, H, DIN,
        us1, ui1, ls1, li1, ubn, lbn, pU1, pL1);

    size_t ssM = (size_t)2 * H * NP1;   // medium-GEMM slab (splits=4)
    size_t ssB = (size_t)2 * H * H;     // big-GEMM slab (splits=2)
    size_t ss4H = (size_t)MP4 * H;      // layer-4 N=H slab
    size_t ss4N = (size_t)MP4 * NP1;    // layer-4 N=NP1 slab

    // ======== Layer 2 ========
    k_interval_affine<<<dim3(H / 4), blk, 0, stream>>>(W2, B2, pU1, pL1, H, H, bU2, bL2);
    k_prep16<<<dim3(2 * H / 16), blk, 0, stream>>>(W2, B2, H,
        nullptr, nullptr, nullptr, nullptr, us1, ui1, ls1, li1, B1, Ab, av);
    gemm(Ab, W1t, Cs, NP1, 2 * H, 4);
    k_reduce16<<<dim3(2 * H / 4), blk, 0, stream>>>(Cs, NP1, DIN, H, 4, ssM, av, ubn, lbn, bU2, bL2);
    k_spu<<<dim3(H / 256), blk, 0, stream>>>(bU2, bL2, H, us2, ui2, ls2, li2, pU2, pL2);
    k_prep16<<<dim3(2 * H / 16), blk, 0, stream>>>(W2, B2, H,
        us2, ui2, ls2, li2, us1, ui1, ls1, li1, B1, Ab, av);
    gemm(Ab, W1t, Cs, NP1, 2 * H, 4);
    k_reduce16<<<dim3(2 * H / 4), blk, 0, stream>>>(Cs, NP1, DIN, H, 4, ssM, av, ubn, lbn, pU2, pL2);

    // ======== Layer 3 ========
    k_interval_affine<<<dim3(H / 4), blk, 0, stream>>>(W3, B3, pU2, pL2, H, H, bU3, bL3);
    k_prep16<<<dim3(2 * H / 16), blk, 0, stream>>>(W3, B3, H,
        nullptr, nullptr, nullptr, nullptr, us2, ui2, ls2, li2, B2, Ab, av);
    gemm(Ab, W2t, Cs, H, 2 * H, 2);
    k_colmix16<<<dim3(2 * H / 16, 1), blk, 0, stream>>>(Cs, H, 2, ssB, H, KTILES,
        us1, ui1, ls1, li1, B1, Ab, av);
    gemm(Ab, W1t, Cs, NP1, 2 * H, 4);
    k_reduce16<<<dim3(2 * H / 4), blk, 0, stream>>>(Cs, NP1, DIN, H, 4, ssM, av, ubn, lbn, bU3, bL3);
    k_spu<<<dim3(H / 256), blk, 0, stream>>>(bU3, bL3, H, us3, ui3, ls3, li3, pU3, pL3);
    k_prep16<<<dim3(2 * H / 16), blk, 0, stream>>>(W3, B3, H,
        us3, ui3, ls3, li3, us2, ui2, ls2, li2, B2, Ab, av);
    gemm(Ab, W2t, Cs, H, 2 * H, 2);
    k_colmix16<<<dim3(2 * H / 16, 1), blk, 0, stream>>>(Cs, H, 2, ssB, H, KTILES,
        us1, ui1, ls1, li1, B1, Ab, av);
    gemm(Ab, W1t, Cs, NP1, 2 * H, 4);
    k_reduce16<<<dim3(2 * H / 4), blk, 0, stream>>>(Cs, NP1, DIN, H, 4, ssM, av, ubn, lbn, pU3, pL3);

    // ======== Layer 4 (M = 20 padded to 128, split-K 16, colmix k-split 8) ========
    k_interval_affine<<<dim3(3), blk, 0, stream>>>(W4, B4, pU3, pL3, H, DOUT, bU4, bL4);
    k_prep16<<<dim3(MP4 / 16), blk, 0, stream>>>(W4, B4, DOUT,
        nullptr, nullptr, nullptr, nullptr, us3, ui3, ls3, li3, B3, Ab, av);
    gemm(Ab, W3t, Cs, H, MP4, 16);
    k_colmix16<<<dim3(MP4 / 16, 8), blk, 0, stream>>>(Cs, H, 16, ss4H, DOUT, KTILES / 8,
        us2, ui2, ls2, li2, B2, Ab, av);
    gemm(Ab, W2t, Cs, H, MP4, 16);
    k_colmix16<<<dim3(MP4 / 16, 8), blk, 0, stream>>>(Cs, H, 16, ss4H, DOUT, KTILES / 8,
        us1, ui1, ls1, li1, B1, Ab, av);
    gemm(Ab, W1t, Cs, NP1, MP4, 16);
    k_reduce16<<<dim3((2 * DOUT + 3) / 4), blk, 0, stream>>>(Cs, NP1, DIN, DOUT, 16, ss4N,
        av, ubn, lbn, bU4, bL4);

    k_final_min<<<dim3(1), dim3(64), 0, stream>>>(bL4, DOUT, out);
}

// Round 6
// 447.950 us; speedup vs baseline: 1.5175x; 1.5175x over previous
//
#include <hip/hip_runtime.h>
#include <cstdint>
#include <cstddef>

#define MEAN_C 0.1307f
#define SIGMA_C 0.3081f
#define SIG_SCALE_C 5.0f

typedef __bf16 bf16_t;
typedef __bf16 bf16x8 __attribute__((ext_vector_type(8)));
typedef __bf16 bf16x4 __attribute__((ext_vector_type(4)));
typedef float f32x4 __attribute__((ext_vector_type(4)));

__device__ __forceinline__ f32x4 mfma16(bf16x8 a, bf16x8 b, f32x4 c) {
    return __builtin_amdgcn_mfma_f32_16x16x32_bf16(a, b, c, 0, 0, 0);
}

typedef const __attribute__((address_space(1))) void* gvp;
typedef __attribute__((address_space(3))) void* lvp;
__device__ __forceinline__ void g2l16(const void* g, void* l) {
    __builtin_amdgcn_global_load_lds((gvp)g, (lvp)l, 16, 0, 0);
}

// swizzled bf16 operand layout: 16x32 tiles (1KB); chunk index within tile =
// lane = (k-chunk)*16 + row  (16B each). offset(r,k), K = ktiles*32.
__device__ __forceinline__ size_t swz(int r, int k, int ktiles) {
    return (((size_t)(r >> 4) * ktiles + (k >> 5)) << 9)
         + (((k >> 3) & 3) << 7) + ((r & 15) << 3) + (k & 7);
}

#define KTILES 64   // K = 2048

// ---------------- device helpers ----------------

__device__ __forceinline__ float sigmoidf_(float x) {
    if (x >= 0.f) { float e = __expf(-x); return 1.f / (1.f + e); }
    float e = __expf(x); return e / (1.f + e);
}

__device__ __forceinline__ float spu_f(float x) {
    return (x >= 0.f) ? (x * x - 0.5f) : (sigmoidf_(-x) - 1.f);
}

__device__ __forceinline__ float wave_sum(float a) {
    #pragma unroll
    for (int o = 32; o > 0; o >>= 1) a += __shfl_xor(a, o, 64);
    return a;
}

// ---------------- small kernels ----------------

__global__ void k_input_bounds(const float* __restrict__ x, const float* __restrict__ eps,
                               int n, float* __restrict__ ubn, float* __restrict__ lbn) {
    int i = blockIdx.x * blockDim.x + threadIdx.x;
    if (i >= n) return;
    float e = eps[0];
    float ub = fminf(x[i] + e, 1.f);
    float lb = fmaxf(x[i] - e, 0.f);
    ubn[i] = (ub - MEAN_C) / SIGMA_C;
    lbn[i] = (lb - MEAN_C) / SIGMA_C;
}

// wave-per-row interval bound (layer 1 only)
__global__ __launch_bounds__(256) void k_interval_affine(
        const float* __restrict__ W, const float* __restrict__ b,
        const float* __restrict__ U, const float* __restrict__ L,
        int m, int nrows, float* __restrict__ uo, float* __restrict__ lo) {
    int r = (blockIdx.x << 2) + (threadIdx.x >> 6);
    if (r >= nrows) return;
    int lane = threadIdx.x & 63;
    const f32x4* Wr = (const f32x4*)(W + (size_t)r * m);
    const f32x4* U4 = (const f32x4*)U;
    const f32x4* L4 = (const f32x4*)L;
    int nf4 = m >> 2;
    float au = 0.f, al = 0.f;
    for (int j = lane; j < nf4; j += 64) {
        f32x4 wv = Wr[j], uu = U4[j], ll = L4[j];
        #pragma unroll
        for (int u = 0; u < 4; ++u) {
            float w = wv[u];
            float hi = (w > 0.f) ? uu[u] : ll[u];
            float lo2 = (w > 0.f) ? ll[u] : uu[u];
            au = fmaf(w, hi, au);
            al = fmaf(w, lo2, al);
        }
    }
    au = wave_sum(au); al = wave_sum(al);
    if (lane == 0) { uo[r] = au + b[r]; lo[r] = al + b[r]; }
}

// fused analyze_spu + scale-permute backsub shortcut:
// post-SPU chain backsub v_B(u-row i) = us[i]*vraw[us>=0? i : n+i] + ui[i]
// pU = min(new_ub, v_Bu); pL = max(new_lb, v_Bl).
__global__ void k_spu2(const float* __restrict__ Uin, const float* __restrict__ Lin,
                       const float* __restrict__ vraw, int n,
                       float* __restrict__ us, float* __restrict__ ui,
                       float* __restrict__ ls, float* __restrict__ li,
                       float* __restrict__ pU, float* __restrict__ pL) {
    int i = blockIdx.x * blockDim.x + threadIdx.x;
    if (i >= n) return;
    float ux = Uin[i], lx = Lin[i];
    float uy = spu_f(ux), ly = spu_f(lx);
    float new_ub = fmaxf(uy, ly);
    float sj = (uy - ly) / (ux - lx);
    float ij = uy - sj * ux;
    bool right = lx > 0.f;
    bool left = ux <= 0.f;
    bool crossing = (!left) && (!right);
    float mid = 0.5f * (ux + lx);
    float sp = 2.f * mid, ip = -mid * mid - 0.5f;
    float sm = sigmoidf_(mid);
    float ssm = -sm * (1.f - sm);
    float ism = -sm - ssm * mid;
    float new_lb = crossing ? -0.5f : fminf(uy, ly);
    float spu_s = 2.f * ux, ipu = -ux * ux - 0.5f;
    float limit = spu_s * lx + ipu;
    float clm = (fabsf(lx) > ux) ? 1.f : 0.f;
    float clp = sigmoidf_((clm - 0.5f) * 2.f * SIG_SCALE_C) * (ly - limit) + limit;
    bool ptm = clp < -0.5f;
    float D = 4.f * lx * lx - 4.f * clp - 2.f;
    float x2 = (2.f * lx + sqrtf(fmaxf(D, 0.f))) * 0.5f;
    float spt = 2.f * x2, ipt = -x2 * x2 - 0.5f;
    float sjn = (clp + 0.5f) / lx;
    float ijn = -0.5f;
    float s_cl = ptm ? spt : sjn;
    float i_cl = ptm ? ipt : ijn;
    float sl = sigmoidf_(lx);
    float ssl = -sl * (1.f - sl);
    float isl = -sl - ssl * lx;
    float stv = ssl * ux + isl - uy;
    float Lb = lx, Rb = 0.f;
    #pragma unroll
    for (int t = 0; t < 10; ++t) {
        float mm = 0.5f * (Lb + Rb);
        float smm = sigmoidf_(mm);
        float sms = -smm * (1.f - smm);
        float smi = -smm - sms * mm;
        bool mask = (sms * ux + smi - uy) > 0.f;
        Lb = mask ? mm : Lb;
        Rb = mask ? Rb : mm;
    }
    float scp = sigmoidf_(-SIG_SCALE_C) * (Lb - lx) + lx;
    float sc = sigmoidf_(scp);
    float ssc = -sc * (1.f - sc);
    float isc = -sc - ssc * scp;
    bool up = stv > 0.f;
    float s_cu = up ? ssc : sj;
    float i_cu = up ? isc : ij;
    float usv, uiv, lsv, liv;
    if (right)      { usv = sj;   uiv = ij;   lsv = sp;   liv = ip;   }
    else if (left)  { usv = ssm;  uiv = ism;  lsv = sj;   liv = ij;   }
    else            { usv = s_cu; uiv = i_cu; lsv = s_cl; liv = i_cl; }
    us[i] = usv; ui[i] = uiv; ls[i] = lsv; li[i] = liv;
    float vu = vraw[(usv >= 0.f) ? i : n + i];
    float vl = vraw[(lsv >= 0.f) ? n + i : i];
    pU[i] = fminf(new_ub, usv * vu + uiv);
    pL[i] = fmaxf(new_lb, lsv * vl + liv);
}

// ---------------- bf16 producers ----------------

// transpose + convert + swizzle: W (K x N real, ldw) fp32 -> Wt swizzled (Npad x K)
__global__ __launch_bounds__(256) void k_wT(
        const float* __restrict__ W, int N, int ldw,
        bf16_t* __restrict__ Wt) {
    __shared__ bf16_t t[64][72];
    int k0 = blockIdx.x * 64, n0 = blockIdx.y * 64;
    int tid = threadIdx.x;
    int r = tid >> 2;
    int c0 = (tid & 3) * 16;
    const float* Wr = W + (size_t)(k0 + r) * ldw;
    #pragma unroll
    for (int c = 0; c < 16; ++c) {
        int gn = n0 + c0 + c;
        float vv = (gn < N) ? Wr[gn] : 0.f;
        t[c0 + c][r] = (bf16_t)vv;
    }
    __syncthreads();
    #pragma unroll
    for (int p = 0; p < 2; ++p) {
        int c = tid + p * 256;
        int lr = c & 63, lq = c >> 6;
        bf16x8 v;
        #pragma unroll
        for (int u = 0; u < 8; ++u) v[u] = t[lr][lq * 8 + u];
        *(bf16x8*)(Wt + swz(n0 + lr, k0 + lq * 8, KTILES)) = v;
    }
}

// prep (fused interval-affine): one 16-row tile per block; lane owns chunk lane
// of each k-tile. Outputs: swizzled bf16 Ab, av[r] (intercept+bvec dots + b),
// iU/iL (interval bounds of this affine layer given U/L).
__global__ __launch_bounds__(256) void k_prep16(
        const float* __restrict__ W, const float* __restrict__ b, int n,
        const float* __restrict__ cus, const float* __restrict__ cui,
        const float* __restrict__ cls, const float* __restrict__ cli,
        const float* __restrict__ bvec,
        const float* __restrict__ U, const float* __restrict__ L,
        bf16_t* __restrict__ Ab, float* __restrict__ av,
        float* __restrict__ iU, float* __restrict__ iL) {
    int rt = blockIdx.x;
    int tid = threadIdx.x, lane = tid & 63, wid = tid >> 6;
    int mrow = lane & 15, q = lane >> 4;
    int r = rt * 16 + mrow;
    bool act = r < 2 * n;
    bool isU = r < n;
    int i = act ? (isU ? r : r - n) : 0;
    float gate = act ? 1.f : 0.f;
    const float* Wr = W + (size_t)i * 2048;
    const float* ps = isU ? cus : cls;
    const float* ns = isU ? cls : cus;
    const float* yi = isU ? cui : cli;
    const float* zi = isU ? cli : cui;
    const float* hi = isU ? U : L;
    const float* lo = isU ? L : U;
    float a = 0.f, a2 = 0.f;
    bf16_t* Abase = Ab + ((size_t)rt * KTILES) * 512 + lane * 8;
    for (int kt = wid; kt < KTILES; kt += 4) {
        int k0 = kt * 32 + q * 8;
        bf16x8 ov;
        #pragma unroll
        for (int h = 0; h < 2; ++h) {
            int kb = k0 + 4 * h;
            f32x4 wv = *(const f32x4*)(Wr + kb);
            f32x4 p0 = *(const f32x4*)(ps + kb);
            f32x4 q0 = *(const f32x4*)(ns + kb);
            f32x4 y0 = *(const f32x4*)(yi + kb);
            f32x4 z0 = *(const f32x4*)(zi + kb);
            f32x4 c0 = *(const f32x4*)(bvec + kb);
            f32x4 h0 = *(const f32x4*)(hi + kb);
            f32x4 l0 = *(const f32x4*)(lo + kb);
            #pragma unroll
            for (int u = 0; u < 4; ++u) {
                float w = gate * wv[u];
                float pos = fmaxf(w, 0.f), neg = fminf(w, 0.f);
                float mx = pos * p0[u] + neg * q0[u];
                ov[4 * h + u] = (bf16_t)mx;
                a += pos * y0[u] + neg * z0[u] + mx * c0[u];
                a2 += pos * h0[u] + neg * l0[u];   // interval dot
            }
        }
        *(bf16x8*)(Abase + (size_t)kt * 512) = ov;
    }
    a += __shfl_xor(a, 16, 64);  a += __shfl_xor(a, 32, 64);
    a2 += __shfl_xor(a2, 16, 64); a2 += __shfl_xor(a2, 32, 64);
    __shared__ float sh[2][4][16];
    if (lane < 16) { sh[0][wid][lane] = a; sh[1][wid][lane] = a2; }
    __syncthreads();
    if (tid < 16) {
        int r2 = rt * 16 + tid;
        float ta = sh[0][0][tid] + sh[0][1][tid] + sh[0][2][tid] + sh[0][3][tid];
        float tb = sh[1][0][tid] + sh[1][1][tid] + sh[1][2][tid] + sh[1][3][tid];
        if (r2 < 2 * n) {
            bool isU2 = r2 < n;
            int i2 = isU2 ? r2 : r2 - n;
            av[r2] = ta + b[i2];
            if (isU2) iU[i2] = tb + b[i2];
            else      iL[i2] = tb + b[i2];
        } else {
            av[r2] = 0.f;
        }
    }
}

// colmix: bf16 split slabs summed in fp32 -> swizzled bf16 Ab; av += dots (atomic)
__global__ __launch_bounds__(256) void k_colmix16(
        const bf16_t* __restrict__ Cb, int ldc, int splits, size_t sstride, int n,
        int tpb,
        const float* __restrict__ cus, const float* __restrict__ cui,
        const float* __restrict__ cls, const float* __restrict__ cli,
        const float* __restrict__ bvec,
        bf16_t* __restrict__ Ab, float* __restrict__ av) {
    int rt = blockIdx.x;
    int kt0 = blockIdx.y * tpb;
    int tid = threadIdx.x, lane = tid & 63, wid = tid >> 6;
    int mrow = lane & 15, q = lane >> 4;
    int r = rt * 16 + mrow;
    bool isU = r < n;
    const bf16_t* Cr = Cb + (size_t)r * ldc;
    const float* ps = isU ? cus : cls;
    const float* ns = isU ? cls : cus;
    const float* yi = isU ? cui : cli;
    const float* zi = isU ? cli : cui;
    float a = 0.f;
    bf16_t* Abase = Ab + ((size_t)rt * KTILES) * 512 + lane * 8;
    for (int kt = kt0 + wid; kt < kt0 + tpb; kt += 4) {
        int k0 = kt * 32 + q * 8;
        float wsum[8] = {0.f, 0.f, 0.f, 0.f, 0.f, 0.f, 0.f, 0.f};
        for (int s = 0; s < splits; ++s) {
            bf16x8 v = *(const bf16x8*)(Cr + s * sstride + k0);
            #pragma unroll
            for (int u = 0; u < 8; ++u) wsum[u] += (float)v[u];
        }
        f32x4 p0 = *(const f32x4*)(ps + k0), p1 = *(const f32x4*)(ps + k0 + 4);
        f32x4 q0 = *(const f32x4*)(ns + k0), q1 = *(const f32x4*)(ns + k0 + 4);
        f32x4 y0 = *(const f32x4*)(yi + k0), y1 = *(const f32x4*)(yi + k0 + 4);
        f32x4 z0 = *(const f32x4*)(zi + k0), z1 = *(const f32x4*)(zi + k0 + 4);
        f32x4 c0 = *(const f32x4*)(bvec + k0), c1 = *(const f32x4*)(bvec + k0 + 4);
        bf16x8 ov;
        #pragma unroll
        for (int u = 0; u < 4; ++u) {
            float w = wsum[u];
            float pos = fmaxf(w, 0.f), neg = fminf(w, 0.f);
            float mx = pos * p0[u] + neg * q0[u];
            ov[u] = (bf16_t)mx;
            a += pos * y0[u] + neg * z0[u] + mx * c0[u];
        }
        #pragma unroll
        for (int u = 0; u < 4; ++u) {
            float w = wsum[4 + u];
            float pos = fmaxf(w, 0.f), neg = fminf(w, 0.f);
            float mx = pos * p1[u] + neg * q1[u];
            ov[4 + u] = (bf16_t)mx;
            a += pos * y1[u] + neg * z1[u] + mx * c1[u];
        }
        *(bf16x8*)(Abase + (size_t)kt * 512) = ov;
    }
    a += __shfl_xor(a, 16, 64);
    a += __shfl_xor(a, 32, 64);
    __shared__ float sh[4][16];
    if (lane < 16) sh[wid][lane] = a;
    __syncthreads();
    if (tid < 16) {
        float tot = sh[0][tid] + sh[1][tid] + sh[2][tid] + sh[3][tid];
        atomicAdd(&av[rt * 16 + tid], tot);
    }
}

// final c0 step: bf16 slabs summed + av -> raw chain value vraw[r], and
// combined bounds bU = min(iU, v), bL = max(iL, v).
__global__ __launch_bounds__(256) void k_reduce16(
        const bf16_t* __restrict__ Cb, int ldc, int m, int n,
        int splits, size_t sstride,
        const float* __restrict__ av,
        const float* __restrict__ ubn, const float* __restrict__ lbn,
        const float* __restrict__ iU, const float* __restrict__ iL,
        float* __restrict__ vraw,
        float* __restrict__ bU, float* __restrict__ bL) {
    int r = (blockIdx.x << 2) + (threadIdx.x >> 6);
    if (r >= 2 * n) return;
    int lane = threadIdx.x & 63;
    bool isU = r < n;
    int i = isU ? r : r - n;
    const bf16_t* Cr = Cb + (size_t)r * ldc;
    const float* p = isU ? ubn : lbn;
    const float* q = isU ? lbn : ubn;
    int nch = m >> 3;   // m % 8 == 0
    float a = 0.f;
    for (int c = lane; c < nch; c += 64) {
        float wsum[8] = {0.f, 0.f, 0.f, 0.f, 0.f, 0.f, 0.f, 0.f};
        for (int s = 0; s < splits; ++s) {
            bf16x8 v = *(const bf16x8*)(Cr + s * sstride + c * 8);
            #pragma unroll
            for (int u = 0; u < 8; ++u) wsum[u] += (float)v[u];
        }
        f32x4 p0 = *(const f32x4*)(p + c * 8), p1 = *(const f32x4*)(p + c * 8 + 4);
        f32x4 q0 = *(const f32x4*)(q + c * 8), q1 = *(const f32x4*)(q + c * 8 + 4);
        #pragma unroll
        for (int u = 0; u < 4; ++u) {
            a += fmaxf(wsum[u], 0.f) * p0[u] + fminf(wsum[u], 0.f) * q0[u];
            a += fmaxf(wsum[4 + u], 0.f) * p1[u] + fminf(wsum[4 + u], 0.f) * q1[u];
        }
    }
    a = wave_sum(a);
    if (lane == 0) {
        float v = a + av[r];
        vraw[r] = v;
        if (isU) bU[i] = fminf(iU[i], v);
        else     bL[i] = fmaxf(iL[i], v);
    }
}

__global__ void k_final_min(const float* __restrict__ l, int n, float* __restrict__ out) {
    float v = 3.4e38f;
    for (int j = threadIdx.x; j < n; j += 64) v = fminf(v, l[j]);
    #pragma unroll
    for (int o = 32; o > 0; o >>= 1) v = fminf(v, __shfl_down(v, o, 64));
    if (threadIdx.x == 0) out[0] = v;
}

// ---------------- bf16 MFMA GEMM, global_load_lds staging, bf16 slab output ----
__global__ __launch_bounds__(256) void k_gemm16(
        const bf16_t* __restrict__ A, const bf16_t* __restrict__ Bt,
        bf16_t* __restrict__ C, int ldc, size_t sstride, int nk) {
    __shared__ __align__(16) bf16_t As[4096];
    __shared__ __align__(16) bf16_t Bs[4096];
    int tid = threadIdx.x, lane = tid & 63, w = tid >> 6;
    int wm = w & 1, wn = w >> 1;
    int tr0 = blockIdx.y * 8, tc0 = blockIdx.x * 8;
    int kt0 = blockIdx.z * nk;

    const bf16_t* a0 = A + (((size_t)(tr0 + w)     * KTILES + kt0) << 9) + lane * 8;
    const bf16_t* a1 = A + (((size_t)(tr0 + w + 4) * KTILES + kt0) << 9) + lane * 8;
    const bf16_t* b0 = Bt + (((size_t)(tc0 + w)     * KTILES + kt0) << 9) + lane * 8;
    const bf16_t* b1 = Bt + (((size_t)(tc0 + w + 4) * KTILES + kt0) << 9) + lane * 8;
    bf16_t* lA0 = &As[w * 512];
    bf16_t* lA1 = &As[(w + 4) * 512];
    bf16_t* lB0 = &Bs[w * 512];
    bf16_t* lB1 = &Bs[(w + 4) * 512];

    f32x4 acc[4][4];
    #pragma unroll
    for (int i = 0; i < 4; ++i)
        #pragma unroll
        for (int j = 0; j < 4; ++j) acc[i][j] = (f32x4){0.f, 0.f, 0.f, 0.f};

    for (int kk = 0; kk < nk; ++kk) {
        g2l16(a0 + (size_t)kk * 512, lA0);
        g2l16(a1 + (size_t)kk * 512, lA1);
        g2l16(b0 + (size_t)kk * 512, lB0);
        g2l16(b1 + (size_t)kk * 512, lB1);
        __syncthreads();
        bf16x8 af[4], bfr[4];
        #pragma unroll
        for (int i = 0; i < 4; ++i)
            af[i] = *(const bf16x8*)(&As[(wm * 4 + i) * 512 + lane * 8]);
        #pragma unroll
        for (int j = 0; j < 4; ++j)
            bfr[j] = *(const bf16x8*)(&Bs[(wn * 4 + j) * 512 + lane * 8]);
        #pragma unroll
        for (int i = 0; i < 4; ++i)
            #pragma unroll
            for (int j = 0; j < 4; ++j)
                acc[i][j] = mfma16(bfr[j], af[i], acc[i][j]);   // swapped -> D^T layout
        __syncthreads();
    }
    bf16_t* Cz = C + (size_t)blockIdx.z * sstride;
    int orow = lane & 15, ocol = (lane >> 4) * 4;
    size_t row0 = (size_t)blockIdx.y * 128;
    size_t col0 = (size_t)blockIdx.x * 128;
    #pragma unroll
    for (int i = 0; i < 4; ++i) {
        size_t gr = row0 + wm * 64 + i * 16 + orow;
        #pragma unroll
        for (int j = 0; j < 4; ++j) {
            size_t gc = col0 + wn * 64 + j * 16 + ocol;
            bf16x4 v;
            #pragma unroll
            for (int rg = 0; rg < 4; ++rg) v[rg] = (bf16_t)acc[i][j][rg];
            *(bf16x4*)(Cz + gr * (size_t)ldc + gc) = v;
        }
    }
}

// ---------------- host launch ----------------

extern "C" void kernel_launch(void* const* d_in, const int* in_sizes, int n_in,
                              void* d_out, int out_size, void* d_ws, size_t ws_size,
                              hipStream_t stream) {
    (void)in_sizes; (void)n_in; (void)out_size; (void)ws_size;
    const float* x   = (const float*)d_in[0];
    const float* eps = (const float*)d_in[1];
    const float* W1  = (const float*)d_in[2];
    const float* B1  = (const float*)d_in[3];
    const float* W2  = (const float*)d_in[4];
    const float* B2  = (const float*)d_in[5];
    const float* W3  = (const float*)d_in[6];
    const float* B3  = (const float*)d_in[7];
    const float* W4  = (const float*)d_in[8];
    const float* B4  = (const float*)d_in[9];
    float* out = (float*)d_out;

    const int H = 2048, DIN = 784, DOUT = 10;
    const int NP1 = 896;           // DIN padded to x128
    const int MP4 = 128;           // layer-4 row pad

    float* ws = (float*)d_ws;
    size_t off = 0;
    auto alloc = [&](size_t nf) -> float* {
        float* p = ws + off;
        off += (nf + 3) & ~(size_t)3;
        return p;
    };
    float* ubn = alloc(DIN);
    float* lbn = alloc(DIN);
    float* vraw1 = alloc(2 * H);   // L1 chain backsub raw (= interval bounds)
    float* us1 = alloc(H); float* ui1 = alloc(H); float* ls1 = alloc(H); float* li1 = alloc(H);
    float* pU1 = alloc(H); float* pL1 = alloc(H);
    float* iU2 = alloc(H); float* iL2 = alloc(H);
    float* vraw2 = alloc(2 * H);
    float* bU2 = alloc(H); float* bL2 = alloc(H);
    float* us2 = alloc(H); float* ui2 = alloc(H); float* ls2 = alloc(H); float* li2 = alloc(H);
    float* pU2 = alloc(H); float* pL2 = alloc(H);
    float* iU3 = alloc(H); float* iL3 = alloc(H);
    float* vraw3 = alloc(2 * H);
    float* bU3 = alloc(H); float* bL3 = alloc(H);
    float* us3 = alloc(H); float* ui3 = alloc(H); float* ls3 = alloc(H); float* li3 = alloc(H);
    float* pU3 = alloc(H); float* pL3 = alloc(H);
    float* iU4 = alloc(32); float* iL4 = alloc(32);
    float* vraw4 = alloc(64);
    float* bU4 = alloc(32); float* bL4 = alloc(32);
    float* av  = alloc(2 * H);
    bf16_t* Ab  = (bf16_t*)alloc((size_t)2 * H * H / 2);       // 4096 x 2048 bf16 swz
    bf16_t* W1t = (bf16_t*)alloc((size_t)NP1 * H / 2);
    bf16_t* W2t = (bf16_t*)alloc((size_t)H * H / 2);
    bf16_t* W3t = (bf16_t*)alloc((size_t)H * H / 2);
    bf16_t* Cs  = (bf16_t*)alloc((size_t)2 * H * H);           // bf16 slab space

    dim3 blk(256);
    auto gemm = [&](const bf16_t* A, const bf16_t* Bt, bf16_t* C, int N, int Mpad, int splits) {
        dim3 g(N / 128, Mpad / 128, splits);
        k_gemm16<<<g, blk, 0, stream>>>(A, Bt, C, N, (size_t)Mpad * N, KTILES / splits);
    };

    // weight transpose/convert/swizzle
    k_wT<<<dim3(H / 64, NP1 / 64), blk, 0, stream>>>(W1, DIN, DIN, W1t);
    k_wT<<<dim3(H / 64, H / 64), blk, 0, stream>>>(W2, H, H, W2t);
    k_wT<<<dim3(H / 64, H / 64), blk, 0, stream>>>(W3, H, H, W3t);

    k_input_bounds<<<dim3((DIN + 255) / 256), blk, 0, stream>>>(x, eps, DIN, ubn, lbn);

    size_t ssM = (size_t)2 * H * NP1;   // medium-GEMM slab (splits=4)
    size_t ssB = (size_t)2 * H * H;     // big-GEMM slab (splits=2)
    size_t ss4H = (size_t)MP4 * H;      // layer-4 N=H slab
    size_t ss4N = (size_t)MP4 * NP1;    // layer-4 N=NP1 slab

    // ======== Layer 1 ========
    // interval affine = exact [c0,c1] chain backsub; store u-rows in vraw1[0:H], l in [H:2H]
    k_interval_affine<<<dim3(H / 4), blk, 0, stream>>>(W1, B1, ubn, lbn, DIN, H,
                                                       vraw1, vraw1 + H);
    k_spu2<<<dim3(H / 256), blk, 0, stream>>>(vraw1, vraw1 + H, vraw1, H,
        us1, ui1, ls1, li1, pU1, pL1);

    // ======== Layer 2 ========
    k_prep16<<<dim3(2 * H / 16), blk, 0, stream>>>(W2, B2, H,
        us1, ui1, ls1, li1, B1, pU1, pL1, Ab, av, iU2, iL2);
    gemm(Ab, W1t, Cs, NP1, 2 * H, 4);
    k_reduce16<<<dim3(2 * H / 4), blk, 0, stream>>>(Cs, NP1, DIN, H, 4, ssM, av,
        ubn, lbn, iU2, iL2, vraw2, bU2, bL2);
    k_spu2<<<dim3(H / 256), blk, 0, stream>>>(bU2, bL2, vraw2, H,
        us2, ui2, ls2, li2, pU2, pL2);

    // ======== Layer 3 ========
    k_prep16<<<dim3(2 * H / 16), blk, 0, stream>>>(W3, B3, H,
        us2, ui2, ls2, li2, B2, pU2, pL2, Ab, av, iU3, iL3);
    gemm(Ab, W2t, Cs, H, 2 * H, 2);
    k_colmix16<<<dim3(2 * H / 16, 1), blk, 0, stream>>>(Cs, H, 2, ssB, H, KTILES,
        us1, ui1, ls1, li1, B1, Ab, av);
    gemm(Ab, W1t, Cs, NP1, 2 * H, 4);
    k_reduce16<<<dim3(2 * H / 4), blk, 0, stream>>>(Cs, NP1, DIN, H, 4, ssM, av,
        ubn, lbn, iU3, iL3, vraw3, bU3, bL3);
    k_spu2<<<dim3(H / 256), blk, 0, stream>>>(bU3, bL3, vraw3, H,
        us3, ui3, ls3, li3, pU3, pL3);

    // ======== Layer 4 (M = 20 padded to 128, split-K 16, colmix k-split 8) ========
    k_prep16<<<dim3(MP4 / 16), blk, 0, stream>>>(W4, B4, DOUT,
        us3, ui3, ls3, li3, B3, pU3, pL3, Ab, av, iU4, iL4);
    gemm(Ab, W3t, Cs, H, MP4, 16);
    k_colmix16<<<dim3(MP4 / 16, 8), blk, 0, stream>>>(Cs, H, 16, ss4H, DOUT, KTILES / 8,
        us2, ui2, ls2, li2, B2, Ab, av);
    gemm(Ab, W2t, Cs, H, MP4, 16);
    k_colmix16<<<dim3(MP4 / 16, 8), blk, 0, stream>>>(Cs, H, 16, ss4H, DOUT, KTILES / 8,
        us1, ui1, ls1, li1, B1, Ab, av);
    gemm(Ab, W1t, Cs, NP1, MP4, 16);
    k_reduce16<<<dim3((2 * DOUT + 3) / 4), blk, 0, stream>>>(Cs, NP1, DIN, DOUT, 16, ss4N,
        av, ubn, lbn, iU4, iL4, vraw4, bU4, bL4);

    k_final_min<<<dim3(1), dim3(64), 0, stream>>>(bL4, DOUT, out);
}

// Round 8
// 380.379 us; speedup vs baseline: 1.7870x; 1.1776x over previous
//
#include <hip/hip_runtime.h>
#include <cstdint>
#include <cstddef>

#define MEAN_C 0.1307f
#define SIGMA_C 0.3081f
#define SIG_SCALE_C 5.0f

typedef __bf16 bf16_t;
typedef __bf16 bf16x8 __attribute__((ext_vector_type(8)));
typedef __bf16 bf16x4 __attribute__((ext_vector_type(4)));
typedef float f32x4 __attribute__((ext_vector_type(4)));

__device__ __forceinline__ f32x4 mfma16(bf16x8 a, bf16x8 b, f32x4 c) {
    return __builtin_amdgcn_mfma_f32_16x16x32_bf16(a, b, c, 0, 0, 0);
}

typedef const __attribute__((address_space(1))) void* gvp;
typedef __attribute__((address_space(3))) void* lvp;
__device__ __forceinline__ void g2l16(const void* g, void* l) {
    __builtin_amdgcn_global_load_lds((gvp)g, (lvp)l, 16, 0, 0);
}

// swizzled bf16 operand layout: 16x32 tiles (1KB); chunk index within tile =
// lane = (k-chunk)*16 + row  (16B each). offset(r,k), K = ktiles*32.
__device__ __forceinline__ size_t swz(int r, int k, int ktiles) {
    return (((size_t)(r >> 4) * ktiles + (k >> 5)) << 9)
         + (((k >> 3) & 3) << 7) + ((r & 15) << 3) + (k & 7);
}

#define KTILES 64   // K = 2048

// ---------------- device helpers ----------------

__device__ __forceinline__ float sigmoidf_(float x) {
    if (x >= 0.f) { float e = __expf(-x); return 1.f / (1.f + e); }
    float e = __expf(x); return e / (1.f + e);
}

__device__ __forceinline__ float spu_f(float x) {
    return (x >= 0.f) ? (x * x - 0.5f) : (sigmoidf_(-x) - 1.f);
}

__device__ __forceinline__ float wave_sum(float a) {
    #pragma unroll
    for (int o = 32; o > 0; o >>= 1) a += __shfl_xor(a, o, 64);
    return a;
}

// ---------------- small kernels ----------------

__global__ void k_input_bounds(const float* __restrict__ x, const float* __restrict__ eps,
                               int n, float* __restrict__ ubn, float* __restrict__ lbn) {
    int i = blockIdx.x * blockDim.x + threadIdx.x;
    if (i >= n) return;
    float e = eps[0];
    float ub = fminf(x[i] + e, 1.f);
    float lb = fmaxf(x[i] - e, 0.f);
    ubn[i] = (ub - MEAN_C) / SIGMA_C;
    lbn[i] = (lb - MEAN_C) / SIGMA_C;
}

// wave-per-row interval bound (layer 1 only)
__global__ __launch_bounds__(256) void k_interval_affine(
        const float* __restrict__ W, const float* __restrict__ b,
        const float* __restrict__ U, const float* __restrict__ L,
        int m, int nrows, float* __restrict__ uo, float* __restrict__ lo) {
    int r = (blockIdx.x << 2) + (threadIdx.x >> 6);
    if (r >= nrows) return;
    int lane = threadIdx.x & 63;
    const f32x4* Wr = (const f32x4*)(W + (size_t)r * m);
    const f32x4* U4 = (const f32x4*)U;
    const f32x4* L4 = (const f32x4*)L;
    int nf4 = m >> 2;
    float au = 0.f, al = 0.f;
    for (int j = lane; j < nf4; j += 64) {
        f32x4 wv = Wr[j], uu = U4[j], ll = L4[j];
        #pragma unroll
        for (int u = 0; u < 4; ++u) {
            float w = wv[u];
            float hi = (w > 0.f) ? uu[u] : ll[u];
            float lo2 = (w > 0.f) ? ll[u] : uu[u];
            au = fmaf(w, hi, au);
            al = fmaf(w, lo2, al);
        }
    }
    au = wave_sum(au); al = wave_sum(al);
    if (lane == 0) { uo[r] = au + b[r]; lo[r] = al + b[r]; }
}

// fused analyze_spu + scale-permute backsub shortcut
__global__ void k_spu2(const float* __restrict__ Uin, const float* __restrict__ Lin,
                       const float* __restrict__ vraw, int n,
                       float* __restrict__ us, float* __restrict__ ui,
                       float* __restrict__ ls, float* __restrict__ li,
                       float* __restrict__ pU, float* __restrict__ pL) {
    int i = blockIdx.x * blockDim.x + threadIdx.x;
    if (i >= n) return;
    float ux = Uin[i], lx = Lin[i];
    float uy = spu_f(ux), ly = spu_f(lx);
    float new_ub = fmaxf(uy, ly);
    float sj = (uy - ly) / (ux - lx);
    float ij = uy - sj * ux;
    bool right = lx > 0.f;
    bool left = ux <= 0.f;
    bool crossing = (!left) && (!right);
    float mid = 0.5f * (ux + lx);
    float sp = 2.f * mid, ip = -mid * mid - 0.5f;
    float sm = sigmoidf_(mid);
    float ssm = -sm * (1.f - sm);
    float ism = -sm - ssm * mid;
    float new_lb = crossing ? -0.5f : fminf(uy, ly);
    float spu_s = 2.f * ux, ipu = -ux * ux - 0.5f;
    float limit = spu_s * lx + ipu;
    float clm = (fabsf(lx) > ux) ? 1.f : 0.f;
    float clp = sigmoidf_((clm - 0.5f) * 2.f * SIG_SCALE_C) * (ly - limit) + limit;
    bool ptm = clp < -0.5f;
    float D = 4.f * lx * lx - 4.f * clp - 2.f;
    float x2 = (2.f * lx + sqrtf(fmaxf(D, 0.f))) * 0.5f;
    float spt = 2.f * x2, ipt = -x2 * x2 - 0.5f;
    float sjn = (clp + 0.5f) / lx;
    float ijn = -0.5f;
    float s_cl = ptm ? spt : sjn;
    float i_cl = ptm ? ipt : ijn;
    float sl = sigmoidf_(lx);
    float ssl = -sl * (1.f - sl);
    float isl = -sl - ssl * lx;
    float stv = ssl * ux + isl - uy;
    float Lb = lx, Rb = 0.f;
    #pragma unroll
    for (int t = 0; t < 10; ++t) {
        float mm = 0.5f * (Lb + Rb);
        float smm = sigmoidf_(mm);
        float sms = -smm * (1.f - smm);
        float smi = -smm - sms * mm;
        bool mask = (sms * ux + smi - uy) > 0.f;
        Lb = mask ? mm : Lb;
        Rb = mask ? Rb : mm;
    }
    float scp = sigmoidf_(-SIG_SCALE_C) * (Lb - lx) + lx;
    float sc = sigmoidf_(scp);
    float ssc = -sc * (1.f - sc);
    float isc = -sc - ssc * scp;
    bool up = stv > 0.f;
    float s_cu = up ? ssc : sj;
    float i_cu = up ? isc : ij;
    float usv, uiv, lsv, liv;
    if (right)      { usv = sj;   uiv = ij;   lsv = sp;   liv = ip;   }
    else if (left)  { usv = ssm;  uiv = ism;  lsv = sj;   liv = ij;   }
    else            { usv = s_cu; uiv = i_cu; lsv = s_cl; liv = i_cl; }
    us[i] = usv; ui[i] = uiv; ls[i] = lsv; li[i] = liv;
    float vu = vraw[(usv >= 0.f) ? i : n + i];
    float vl = vraw[(lsv >= 0.f) ? n + i : i];
    pU[i] = fminf(new_ub, usv * vu + uiv);
    pL[i] = fmaxf(new_lb, lsv * vl + liv);
}

// ---------------- bf16 producers ----------------

// transpose + convert + swizzle: W (K x N real, ldw) fp32 -> Wt swizzled (Npad x K)
__global__ __launch_bounds__(256) void k_wT(
        const float* __restrict__ W, int N, int ldw,
        bf16_t* __restrict__ Wt) {
    __shared__ bf16_t t[64][72];
    int k0 = blockIdx.x * 64, n0 = blockIdx.y * 64;
    int tid = threadIdx.x;
    int r = tid >> 2;
    int c0 = (tid & 3) * 16;
    const float* Wr = W + (size_t)(k0 + r) * ldw;
    #pragma unroll
    for (int c = 0; c < 16; ++c) {
        int gn = n0 + c0 + c;
        float vv = (gn < N) ? Wr[gn] : 0.f;
        t[c0 + c][r] = (bf16_t)vv;
    }
    __syncthreads();
    #pragma unroll
    for (int p = 0; p < 2; ++p) {
        int c = tid + p * 256;
        int lr = c & 63, lq = c >> 6;
        bf16x8 v;
        #pragma unroll
        for (int u = 0; u < 8; ++u) v[u] = t[lr][lq * 8 + u];
        *(bf16x8*)(Wt + swz(n0 + lr, k0 + lq * 8, KTILES)) = v;
    }
}

// prep (fused interval-affine)
__global__ __launch_bounds__(256) void k_prep16(
        const float* __restrict__ W, const float* __restrict__ b, int n,
        const float* __restrict__ cus, const float* __restrict__ cui,
        const float* __restrict__ cls, const float* __restrict__ cli,
        const float* __restrict__ bvec,
        const float* __restrict__ U, const float* __restrict__ L,
        bf16_t* __restrict__ Ab, float* __restrict__ av,
        float* __restrict__ iU, float* __restrict__ iL) {
    int rt = blockIdx.x;
    int tid = threadIdx.x, lane = tid & 63, wid = tid >> 6;
    int mrow = lane & 15, q = lane >> 4;
    int r = rt * 16 + mrow;
    bool act = r < 2 * n;
    bool isU = r < n;
    int i = act ? (isU ? r : r - n) : 0;
    float gate = act ? 1.f : 0.f;
    const float* Wr = W + (size_t)i * 2048;
    const float* ps = isU ? cus : cls;
    const float* ns = isU ? cls : cus;
    const float* yi = isU ? cui : cli;
    const float* zi = isU ? cli : cui;
    const float* hi = isU ? U : L;
    const float* lo = isU ? L : U;
    float a = 0.f, a2 = 0.f;
    bf16_t* Abase = Ab + ((size_t)rt * KTILES) * 512 + lane * 8;
    for (int kt = wid; kt < KTILES; kt += 4) {
        int k0 = kt * 32 + q * 8;
        bf16x8 ov;
        #pragma unroll
        for (int h = 0; h < 2; ++h) {
            int kb = k0 + 4 * h;
            f32x4 wv = *(const f32x4*)(Wr + kb);
            f32x4 p0 = *(const f32x4*)(ps + kb);
            f32x4 q0 = *(const f32x4*)(ns + kb);
            f32x4 y0 = *(const f32x4*)(yi + kb);
            f32x4 z0 = *(const f32x4*)(zi + kb);
            f32x4 c0 = *(const f32x4*)(bvec + kb);
            f32x4 h0 = *(const f32x4*)(hi + kb);
            f32x4 l0 = *(const f32x4*)(lo + kb);
            #pragma unroll
            for (int u = 0; u < 4; ++u) {
                float w = gate * wv[u];
                float pos = fmaxf(w, 0.f), neg = fminf(w, 0.f);
                float mx = pos * p0[u] + neg * q0[u];
                ov[4 * h + u] = (bf16_t)mx;
                a += pos * y0[u] + neg * z0[u] + mx * c0[u];
                a2 += pos * h0[u] + neg * l0[u];   // interval dot
            }
        }
        *(bf16x8*)(Abase + (size_t)kt * 512) = ov;
    }
    a += __shfl_xor(a, 16, 64);  a += __shfl_xor(a, 32, 64);
    a2 += __shfl_xor(a2, 16, 64); a2 += __shfl_xor(a2, 32, 64);
    __shared__ float sh[2][4][16];
    if (lane < 16) { sh[0][wid][lane] = a; sh[1][wid][lane] = a2; }
    __syncthreads();
    if (tid < 16) {
        int r2 = rt * 16 + tid;
        float ta = sh[0][0][tid] + sh[0][1][tid] + sh[0][2][tid] + sh[0][3][tid];
        float tb = sh[1][0][tid] + sh[1][1][tid] + sh[1][2][tid] + sh[1][3][tid];
        if (r2 < 2 * n) {
            bool isU2 = r2 < n;
            int i2 = isU2 ? r2 : r2 - n;
            av[r2] = ta + b[i2];
            if (isU2) iU[i2] = tb + b[i2];
            else      iL[i2] = tb + b[i2];
        } else {
            av[r2] = 0.f;
        }
    }
}

// colmix (layer-4 small-M chains): bf16 split slabs -> swizzled bf16 Ab
__global__ __launch_bounds__(256) void k_colmix16(
        const bf16_t* __restrict__ Cb, int ldc, int splits, size_t sstride, int n,
        int tpb,
        const float* __restrict__ cus, const float* __restrict__ cui,
        const float* __restrict__ cls, const float* __restrict__ cli,
        const float* __restrict__ bvec,
        bf16_t* __restrict__ Ab, float* __restrict__ av) {
    int rt = blockIdx.x;
    int kt0 = blockIdx.y * tpb;
    int tid = threadIdx.x, lane = tid & 63, wid = tid >> 6;
    int mrow = lane & 15, q = lane >> 4;
    int r = rt * 16 + mrow;
    bool isU = r < n;
    const bf16_t* Cr = Cb + (size_t)r * ldc;
    const float* ps = isU ? cus : cls;
    const float* ns = isU ? cls : cus;
    const float* yi = isU ? cui : cli;
    const float* zi = isU ? cli : cui;
    float a = 0.f;
    bf16_t* Abase = Ab + ((size_t)rt * KTILES) * 512 + lane * 8;
    for (int kt = kt0 + wid; kt < kt0 + tpb; kt += 4) {
        int k0 = kt * 32 + q * 8;
        float wsum[8] = {0.f, 0.f, 0.f, 0.f, 0.f, 0.f, 0.f, 0.f};
        for (int s = 0; s < splits; ++s) {
            bf16x8 v = *(const bf16x8*)(Cr + s * sstride + k0);
            #pragma unroll
            for (int u = 0; u < 8; ++u) wsum[u] += (float)v[u];
        }
        f32x4 p0 = *(const f32x4*)(ps + k0), p1 = *(const f32x4*)(ps + k0 + 4);
        f32x4 q0 = *(const f32x4*)(ns + k0), q1 = *(const f32x4*)(ns + k0 + 4);
        f32x4 y0 = *(const f32x4*)(yi + k0), y1 = *(const f32x4*)(yi + k0 + 4);
        f32x4 z0 = *(const f32x4*)(zi + k0), z1 = *(const f32x4*)(zi + k0 + 4);
        f32x4 c0 = *(const f32x4*)(bvec + k0), c1 = *(const f32x4*)(bvec + k0 + 4);
        bf16x8 ov;
        #pragma unroll
        for (int u = 0; u < 4; ++u) {
            float w = wsum[u];
            float pos = fmaxf(w, 0.f), neg = fminf(w, 0.f);
            float mx = pos * p0[u] + neg * q0[u];
            ov[u] = (bf16_t)mx;
            a += pos * y0[u] + neg * z0[u] + mx * c0[u];
        }
        #pragma unroll
        for (int u = 0; u < 4; ++u) {
            float w = wsum[4 + u];
            float pos = fmaxf(w, 0.f), neg = fminf(w, 0.f);
            float mx = pos * p1[u] + neg * q1[u];
            ov[4 + u] = (bf16_t)mx;
            a += pos * y1[u] + neg * z1[u] + mx * c1[u];
        }
        *(bf16x8*)(Abase + (size_t)kt * 512) = ov;
    }
    a += __shfl_xor(a, 16, 64);
    a += __shfl_xor(a, 32, 64);
    __shared__ float sh[4][16];
    if (lane < 16) sh[wid][lane] = a;
    __syncthreads();
    if (tid < 16) {
        float tot = sh[0][tid] + sh[1][tid] + sh[2][tid] + sh[3][tid];
        atomicAdd(&av[rt * 16 + tid], tot);
    }
}

// final c0 step
__global__ __launch_bounds__(256) void k_reduce16(
        const bf16_t* __restrict__ Cb, int ldc, int m, int n,
        int splits, size_t sstride,
        const float* __restrict__ av,
        const float* __restrict__ ubn, const float* __restrict__ lbn,
        const float* __restrict__ iU, const float* __restrict__ iL,
        float* __restrict__ vraw,
        float* __restrict__ bU, float* __restrict__ bL) {
    int r = (blockIdx.x << 2) + (threadIdx.x >> 6);
    if (r >= 2 * n) return;
    int lane = threadIdx.x & 63;
    bool isU = r < n;
    int i = isU ? r : r - n;
    const bf16_t* Cr = Cb + (size_t)r * ldc;
    const float* p = isU ? ubn : lbn;
    const float* q = isU ? lbn : ubn;
    int nch = m >> 3;   // m % 8 == 0
    float a = 0.f;
    for (int c = lane; c < nch; c += 64) {
        float wsum[8] = {0.f, 0.f, 0.f, 0.f, 0.f, 0.f, 0.f, 0.f};
        for (int s = 0; s < splits; ++s) {
            bf16x8 v = *(const bf16x8*)(Cr + s * sstride + c * 8);
            #pragma unroll
            for (int u = 0; u < 8; ++u) wsum[u] += (float)v[u];
        }
        f32x4 p0 = *(const f32x4*)(p + c * 8), p1 = *(const f32x4*)(p + c * 8 + 4);
        f32x4 q0 = *(const f32x4*)(q + c * 8), q1 = *(const f32x4*)(q + c * 8 + 4);
        #pragma unroll
        for (int u = 0; u < 4; ++u) {
            a += fmaxf(wsum[u], 0.f) * p0[u] + fminf(wsum[u], 0.f) * q0[u];
            a += fmaxf(wsum[4 + u], 0.f) * p1[u] + fminf(wsum[4 + u], 0.f) * q1[u];
        }
    }
    a = wave_sum(a);
    if (lane == 0) {
        float v = a + av[r];
        vraw[r] = v;
        if (isU) bU[i] = fminf(iU[i], v);
        else     bL[i] = fmaxf(iL[i], v);
    }
}

__global__ void k_final_min(const float* __restrict__ l, int n, float* __restrict__ out) {
    float v = 3.4e38f;
    for (int j = threadIdx.x; j < n; j += 64) v = fminf(v, l[j]);
    #pragma unroll
    for (int o = 32; o > 0; o >>= 1) v = fminf(v, __shfl_down(v, o, 64));
    if (threadIdx.x == 0) out[0] = v;
}

// ---------------- bf16 MFMA GEMM, BK=64 (2 k-tiles per barrier pair) ----------
__global__ __launch_bounds__(256) void k_gemm16(
        const bf16_t* __restrict__ A, const bf16_t* __restrict__ Bt,
        bf16_t* __restrict__ C, int ldc, size_t sstride, int nk) {
    __shared__ __align__(16) bf16_t As[8192];
    __shared__ __align__(16) bf16_t Bs[8192];
    int tid = threadIdx.x, lane = tid & 63, w = tid >> 6;
    int wm = w & 1, wn = w >> 1;
    int tr0 = blockIdx.y * 8, tc0 = blockIdx.x * 8;
    int kt0 = blockIdx.z * nk * 2;

    const bf16_t* a0 = A + (((size_t)(tr0 + w)     * KTILES + kt0) << 9) + lane * 8;
    const bf16_t* a1 = A + (((size_t)(tr0 + w + 4) * KTILES + kt0) << 9) + lane * 8;
    const bf16_t* b0 = Bt + (((size_t)(tc0 + w)     * KTILES + kt0) << 9) + lane * 8;
    const bf16_t* b1 = Bt + (((size_t)(tc0 + w + 4) * KTILES + kt0) << 9) + lane * 8;
    bf16_t* lA0 = &As[w * 1024];
    bf16_t* lA1 = &As[(w + 4) * 1024];
    bf16_t* lB0 = &Bs[w * 1024];
    bf16_t* lB1 = &Bs[(w + 4) * 1024];

    f32x4 acc[4][4];
    #pragma unroll
    for (int i = 0; i < 4; ++i)
        #pragma unroll
        for (int j = 0; j < 4; ++j) acc[i][j] = (f32x4){0.f, 0.f, 0.f, 0.f};

    for (int kk = 0; kk < nk; ++kk) {
        size_t go = (size_t)kk * 1024;
        g2l16(a0 + go, lA0);       g2l16(a0 + go + 512, lA0 + 512);
        g2l16(a1 + go, lA1);       g2l16(a1 + go + 512, lA1 + 512);
        g2l16(b0 + go, lB0);       g2l16(b0 + go + 512, lB0 + 512);
        g2l16(b1 + go, lB1);       g2l16(b1 + go + 512, lB1 + 512);
        __syncthreads();
        #pragma unroll
        for (int h = 0; h < 2; ++h) {
            bf16x8 af[4], bfr[4];
            #pragma unroll
            for (int i = 0; i < 4; ++i)
                af[i] = *(const bf16x8*)(&As[(wm * 4 + i) * 1024 + h * 512 + lane * 8]);
            #pragma unroll
            for (int j = 0; j < 4; ++j)
                bfr[j] = *(const bf16x8*)(&Bs[(wn * 4 + j) * 1024 + h * 512 + lane * 8]);
            #pragma unroll
            for (int i = 0; i < 4; ++i)
                #pragma unroll
                for (int j = 0; j < 4; ++j)
                    acc[i][j] = mfma16(bfr[j], af[i], acc[i][j]);   // swapped -> D^T
        }
        __syncthreads();
    }
    bf16_t* Cz = C + (size_t)blockIdx.z * sstride;
    int orow = lane & 15, ocol = (lane >> 4) * 4;
    size_t row0 = (size_t)blockIdx.y * 128;
    size_t col0 = (size_t)blockIdx.x * 128;
    #pragma unroll
    for (int i = 0; i < 4; ++i) {
        size_t gr = row0 + wm * 64 + i * 16 + orow;
        #pragma unroll
        for (int j = 0; j < 4; ++j) {
            size_t gc = col0 + wn * 64 + j * 16 + ocol;
            bf16x4 v;
            #pragma unroll
            for (int rg = 0; rg < 4; ++rg) v[rg] = (bf16_t)acc[i][j][rg];
            *(bf16x4*)(Cz + gr * (size_t)ldc + gc) = v;
        }
    }
}

// GEMM + fused colmix epilogue (splits=1 only, M=2n rows, N=2048 cols).
// Writes next swizzled operand Ab2 and atomicAdds per-row intercept dots to av.
__global__ __launch_bounds__(256) void k_gemm16_mix(
        const bf16_t* __restrict__ A, const bf16_t* __restrict__ Bt, int n,
        const float* __restrict__ cus, const float* __restrict__ cui,
        const float* __restrict__ cls, const float* __restrict__ cli,
        const float* __restrict__ bvec,
        bf16_t* __restrict__ Ab2, float* __restrict__ av, int nk) {
    __shared__ __align__(16) bf16_t As[8192];
    __shared__ __align__(16) bf16_t Bs[8192];
    __shared__ float asum[2][128];
    int tid = threadIdx.x, lane = tid & 63, w = tid >> 6;
    int wm = w & 1, wn = w >> 1;
    int tr0 = blockIdx.y * 8, tc0 = blockIdx.x * 8;

    const bf16_t* a0 = A + (((size_t)(tr0 + w)     * KTILES) << 9) + lane * 8;
    const bf16_t* a1 = A + (((size_t)(tr0 + w + 4) * KTILES) << 9) + lane * 8;
    const bf16_t* b0 = Bt + (((size_t)(tc0 + w)     * KTILES) << 9) + lane * 8;
    const bf16_t* b1 = Bt + (((size_t)(tc0 + w + 4) * KTILES) << 9) + lane * 8;
    bf16_t* lA0 = &As[w * 1024];
    bf16_t* lA1 = &As[(w + 4) * 1024];
    bf16_t* lB0 = &Bs[w * 1024];
    bf16_t* lB1 = &Bs[(w + 4) * 1024];

    f32x4 acc[4][4];
    #pragma unroll
    for (int i = 0; i < 4; ++i)
        #pragma unroll
        for (int j = 0; j < 4; ++j) acc[i][j] = (f32x4){0.f, 0.f, 0.f, 0.f};

    for (int kk = 0; kk < nk; ++kk) {
        size_t go = (size_t)kk * 1024;
        g2l16(a0 + go, lA0);       g2l16(a0 + go + 512, lA0 + 512);
        g2l16(a1 + go, lA1);       g2l16(a1 + go + 512, lA1 + 512);
        g2l16(b0 + go, lB0);       g2l16(b0 + go + 512, lB0 + 512);
        g2l16(b1 + go, lB1);       g2l16(b1 + go + 512, lB1 + 512);
        __syncthreads();
        #pragma unroll
        for (int h = 0; h < 2; ++h) {
            bf16x8 af[4], bfr[4];
            #pragma unroll
            for (int i = 0; i < 4; ++i)
                af[i] = *(const bf16x8*)(&As[(wm * 4 + i) * 1024 + h * 512 + lane * 8]);
            #pragma unroll
            for (int j = 0; j < 4; ++j)
                bfr[j] = *(const bf16x8*)(&Bs[(wn * 4 + j) * 1024 + h * 512 + lane * 8]);
            #pragma unroll
            for (int i = 0; i < 4; ++i)
                #pragma unroll
                for (int j = 0; j < 4; ++j)
                    acc[i][j] = mfma16(bfr[j], af[i], acc[i][j]);
        }
        __syncthreads();
    }
    // ---- fused colmix epilogue ----
    size_t row0 = (size_t)blockIdx.y * 128;
    size_t col0 = (size_t)blockIdx.x * 128;
    bool isU = (int)row0 < n;            // row0 multiple of 128, n multiple of 128
    const float* ps = isU ? cus : cls;
    const float* ns = isU ? cls : cus;
    const float* yi = isU ? cui : cli;
    const float* zi = isU ? cli : cui;
    int orow = lane & 15, ocol = (lane >> 4) * 4;
    #pragma unroll
    for (int i = 0; i < 4; ++i) {
        int gr = (int)row0 + wm * 64 + i * 16 + orow;
        float ra = 0.f;
        #pragma unroll
        for (int j = 0; j < 4; ++j) {
            int gc = (int)col0 + wn * 64 + j * 16 + ocol;
            f32x4 p0 = *(const f32x4*)(ps + gc);
            f32x4 q0 = *(const f32x4*)(ns + gc);
            f32x4 y0 = *(const f32x4*)(yi + gc);
            f32x4 z0 = *(const f32x4*)(zi + gc);
            f32x4 c0 = *(const f32x4*)(bvec + gc);
            bf16x4 ov;
            #pragma unroll
            for (int rg = 0; rg < 4; ++rg) {
                float v = acc[i][j][rg];
                float pos = fmaxf(v, 0.f), neg = fminf(v, 0.f);
                float mx = pos * p0[rg] + neg * q0[rg];
                ov[rg] = (bf16_t)mx;
                ra += pos * y0[rg] + neg * z0[rg] + mx * c0[rg];
            }
            *(bf16x4*)(Ab2 + swz(gr, gc, KTILES)) = ov;
        }
        ra += __shfl_xor(ra, 16, 64);
        ra += __shfl_xor(ra, 32, 64);
        if (lane < 16) asum[wn][wm * 64 + i * 16 + lane] = ra;
    }
    __syncthreads();
    if (tid < 128) atomicAdd(&av[row0 + tid], asum[0][tid] + asum[1][tid]);
}

// ---------------- host launch ----------------

extern "C" void kernel_launch(void* const* d_in, const int* in_sizes, int n_in,
                              void* d_out, int out_size, void* d_ws, size_t ws_size,
                              hipStream_t stream) {
    (void)in_sizes; (void)n_in; (void)out_size; (void)ws_size;
    const float* x   = (const float*)d_in[0];
    const float* eps = (const float*)d_in[1];
    const float* W1  = (const float*)d_in[2];
    const float* B1  = (const float*)d_in[3];
    const float* W2  = (const float*)d_in[4];
    const float* B2  = (const float*)d_in[5];
    const float* W3  = (const float*)d_in[6];
    const float* B3  = (const float*)d_in[7];
    const float* W4  = (const float*)d_in[8];
    const float* B4  = (const float*)d_in[9];
    float* out = (float*)d_out;

    const int H = 2048, DIN = 784, DOUT = 10;
    const int NP1 = 896;           // DIN padded to x128
    const int MP4 = 128;           // layer-4 row pad

    float* ws = (float*)d_ws;
    size_t off = 0;
    auto alloc = [&](size_t nf) -> float* {
        float* p = ws + off;
        off += (nf + 3) & ~(size_t)3;
        return p;
    };
    float* ubn = alloc(DIN);
    float* lbn = alloc(DIN);
    float* vraw1 = alloc(2 * H);
    float* us1 = alloc(H); float* ui1 = alloc(H); float* ls1 = alloc(H); float* li1 = alloc(H);
    float* pU1 = alloc(H); float* pL1 = alloc(H);
    float* iU2 = alloc(H); float* iL2 = alloc(H);
    float* vraw2 = alloc(2 * H);
    float* bU2 = alloc(H); float* bL2 = alloc(H);
    float* us2 = alloc(H); float* ui2 = alloc(H); float* ls2 = alloc(H); float* li2 = alloc(H);
    float* pU2 = alloc(H); float* pL2 = alloc(H);
    float* iU3 = alloc(H); float* iL3 = alloc(H);
    float* vraw3 = alloc(2 * H);
    float* bU3 = alloc(H); float* bL3 = alloc(H);
    float* us3 = alloc(H); float* ui3 = alloc(H); float* ls3 = alloc(H); float* li3 = alloc(H);
    float* pU3 = alloc(H); float* pL3 = alloc(H);
    float* iU4 = alloc(32); float* iL4 = alloc(32);
    float* vraw4 = alloc(64);
    float* bU4 = alloc(32); float* bL4 = alloc(32);
    float* av  = alloc(2 * H);
    bf16_t* Ab  = (bf16_t*)alloc((size_t)2 * H * H / 2);       // 4096 x 2048 bf16 swz
    bf16_t* Ab2 = (bf16_t*)alloc((size_t)2 * H * H / 2);       // second operand buffer
    bf16_t* W1t = (bf16_t*)alloc((size_t)NP1 * H / 2);
    bf16_t* W2t = (bf16_t*)alloc((size_t)H * H / 2);
    bf16_t* W3t = (bf16_t*)alloc((size_t)H * H / 2);
    bf16_t* Cs  = (bf16_t*)alloc((size_t)2 * H * NP1);         // medium/L4 slab space

    dim3 blk(256);
    auto gemm = [&](const bf16_t* A, const bf16_t* Bt, bf16_t* C, int N, int Mpad, int splits) {
        dim3 g(N / 128, Mpad / 128, splits);
        k_gemm16<<<g, blk, 0, stream>>>(A, Bt, C, N, (size_t)Mpad * N, KTILES / splits / 2);
    };

    // weight transpose/convert/swizzle
    k_wT<<<dim3(H / 64, NP1 / 64), blk, 0, stream>>>(W1, DIN, DIN, W1t);
    k_wT<<<dim3(H / 64, H / 64), blk, 0, stream>>>(W2, H, H, W2t);
    k_wT<<<dim3(H / 64, H / 64), blk, 0, stream>>>(W3, H, H, W3t);

    k_input_bounds<<<dim3((DIN + 255) / 256), blk, 0, stream>>>(x, eps, DIN, ubn, lbn);

    // slab strides are in ELEMENTS and must equal gemm's sstride = Mpad * N
    size_t ssM = (size_t)2 * H * NP1;       // medium slab (splits=2)
    size_t ss4H = (size_t)MP4 * H;          // layer-4 N=H slab
    size_t ss4N = (size_t)MP4 * NP1;        // layer-4 N=NP1 slab

    // ======== Layer 1 ========
    k_interval_affine<<<dim3(H / 4), blk, 0, stream>>>(W1, B1, ubn, lbn, DIN, H,
                                                       vraw1, vraw1 + H);
    k_spu2<<<dim3(H / 256), blk, 0, stream>>>(vraw1, vraw1 + H, vraw1, H,
        us1, ui1, ls1, li1, pU1, pL1);

    // ======== Layer 2 ========
    k_prep16<<<dim3(2 * H / 16), blk, 0, stream>>>(W2, B2, H,
        us1, ui1, ls1, li1, B1, pU1, pL1, Ab, av, iU2, iL2);
    gemm(Ab, W1t, Cs, NP1, 2 * H, 2);
    k_reduce16<<<dim3(2 * H / 4), blk, 0, stream>>>(Cs, NP1, DIN, H, 2, ssM, av,
        ubn, lbn, iU2, iL2, vraw2, bU2, bL2);
    k_spu2<<<dim3(H / 256), blk, 0, stream>>>(bU2, bL2, vraw2, H,
        us2, ui2, ls2, li2, pU2, pL2);

    // ======== Layer 3 ========
    k_prep16<<<dim3(2 * H / 16), blk, 0, stream>>>(W3, B3, H,
        us2, ui2, ls2, li2, B2, pU2, pL2, Ab, av, iU3, iL3);
    k_gemm16_mix<<<dim3(H / 128, 2 * H / 128), blk, 0, stream>>>(Ab, W2t, H,
        us1, ui1, ls1, li1, B1, Ab2, av, KTILES / 2);
    gemm(Ab2, W1t, Cs, NP1, 2 * H, 2);
    k_reduce16<<<dim3(2 * H / 4), blk, 0, stream>>>(Cs, NP1, DIN, H, 2, ssM, av,
        ubn, lbn, iU3, iL3, vraw3, bU3, bL3);
    k_spu2<<<dim3(H / 256), blk, 0, stream>>>(bU3, bL3, vraw3, H,
        us3, ui3, ls3, li3, pU3, pL3);

    // ======== Layer 4 (M = 20 padded to 128, split-K 16, colmix k-split 8) ========
    k_prep16<<<dim3(MP4 / 16), blk, 0, stream>>>(W4, B4, DOUT,
        us3, ui3, ls3, li3, B3, pU3, pL3, Ab, av, iU4, iL4);
    gemm(Ab, W3t, Cs, H, MP4, 16);
    k_colmix16<<<dim3(MP4 / 16, 8), blk, 0, stream>>>(Cs, H, 16, ss4H, DOUT, KTILES / 8,
        us2, ui2, ls2, li2, B2, Ab2, av);
    gemm(Ab2, W2t, Cs, H, MP4, 16);
    k_colmix16<<<dim3(MP4 / 16, 8), blk, 0, stream>>>(Cs, H, 16, ss4H, DOUT, KTILES / 8,
        us1, ui1, ls1, li1, B1, Ab, av);
    gemm(Ab, W1t, Cs, NP1, MP4, 16);
    k_reduce16<<<dim3((2 * DOUT + 3) / 4), blk, 0, stream>>>(Cs, NP1, DIN, DOUT, 16, ss4N,
        av, ubn, lbn, iU4, iL4, vraw4, bU4, bL4);

    k_final_min<<<dim3(1), dim3(64), 0, stream>>>(bL4, DOUT, out);
}

// Round 9
// 376.329 us; speedup vs baseline: 1.8063x; 1.0108x over previous
//
#include <hip/hip_runtime.h>
#include <cstdint>
#include <cstddef>

#define MEAN_C 0.1307f
#define SIGMA_C 0.3081f
#define SIG_SCALE_C 5.0f

typedef __bf16 bf16_t;
typedef __bf16 bf16x8 __attribute__((ext_vector_type(8)));
typedef __bf16 bf16x4 __attribute__((ext_vector_type(4)));
typedef float f32x4 __attribute__((ext_vector_type(4)));

__device__ __forceinline__ f32x4 mfma16(bf16x8 a, bf16x8 b, f32x4 c) {
    return __builtin_amdgcn_mfma_f32_16x16x32_bf16(a, b, c, 0, 0, 0);
}

typedef const __attribute__((address_space(1))) void* gvp;
typedef __attribute__((address_space(3))) void* lvp;
__device__ __forceinline__ void g2l16(const void* g, void* l) {
    __builtin_amdgcn_global_load_lds((gvp)g, (lvp)l, 16, 0, 0);
}

// swizzled bf16 operand layout: 16x32 tiles (1KB); chunk index within tile =
// lane = (k-chunk)*16 + row  (16B each). offset(r,k), K = ktiles*32.
__device__ __forceinline__ size_t swz(int r, int k, int ktiles) {
    return (((size_t)(r >> 4) * ktiles + (k >> 5)) << 9)
         + (((k >> 3) & 3) << 7) + ((r & 15) << 3) + (k & 7);
}

#define KTILES 64   // K = 2048

// ---------------- device helpers ----------------

__device__ __forceinline__ float sigmoidf_(float x) {
    if (x >= 0.f) { float e = __expf(-x); return 1.f / (1.f + e); }
    float e = __expf(x); return e / (1.f + e);
}

__device__ __forceinline__ float spu_f(float x) {
    return (x >= 0.f) ? (x * x - 0.5f) : (sigmoidf_(-x) - 1.f);
}

__device__ __forceinline__ float wave_sum(float a) {
    #pragma unroll
    for (int o = 32; o > 0; o >>= 1) a += __shfl_xor(a, o, 64);
    return a;
}

// ---------------- small kernels ----------------

// bounds padded to np (cols >= n zeroed so padded GEMM cols contribute 0)
__global__ void k_input_bounds(const float* __restrict__ x, const float* __restrict__ eps,
                               int n, int np, float* __restrict__ ubn, float* __restrict__ lbn) {
    int i = blockIdx.x * blockDim.x + threadIdx.x;
    if (i >= np) return;
    if (i >= n) { ubn[i] = 0.f; lbn[i] = 0.f; return; }
    float e = eps[0];
    float ub = fminf(x[i] + e, 1.f);
    float lb = fmaxf(x[i] - e, 0.f);
    ubn[i] = (ub - MEAN_C) / SIGMA_C;
    lbn[i] = (lb - MEAN_C) / SIGMA_C;
}

// wave-per-row interval bound (layer 1 only)
__global__ __launch_bounds__(256) void k_interval_affine(
        const float* __restrict__ W, const float* __restrict__ b,
        const float* __restrict__ U, const float* __restrict__ L,
        int m, int nrows, float* __restrict__ uo, float* __restrict__ lo) {
    int r = (blockIdx.x << 2) + (threadIdx.x >> 6);
    if (r >= nrows) return;
    int lane = threadIdx.x & 63;
    const f32x4* Wr = (const f32x4*)(W + (size_t)r * m);
    const f32x4* U4 = (const f32x4*)U;
    const f32x4* L4 = (const f32x4*)L;
    int nf4 = m >> 2;
    float au = 0.f, al = 0.f;
    for (int j = lane; j < nf4; j += 64) {
        f32x4 wv = Wr[j], uu = U4[j], ll = L4[j];
        #pragma unroll
        for (int u = 0; u < 4; ++u) {
            float w = wv[u];
            float hi = (w > 0.f) ? uu[u] : ll[u];
            float lo2 = (w > 0.f) ? ll[u] : uu[u];
            au = fmaf(w, hi, au);
            al = fmaf(w, lo2, al);
        }
    }
    au = wave_sum(au); al = wave_sum(al);
    if (lane == 0) { uo[r] = au + b[r]; lo[r] = al + b[r]; }
}

// fused: bound-clamp (min/max of interval vs chain value) + analyze_spu +
// scale-permute backsub shortcut.
// ux = min(iU[i], vraw[i]); lx = max(iL[i], vraw[n+i]);
// pU = min(new_ub, us*vraw[perm]+ui); pL = max(new_lb, ls*vraw[perm]+li).
__global__ void k_spu2(const float* __restrict__ iU, const float* __restrict__ iL,
                       const float* __restrict__ vraw, int n,
                       float* __restrict__ us, float* __restrict__ ui,
                       float* __restrict__ ls, float* __restrict__ li,
                       float* __restrict__ pU, float* __restrict__ pL) {
    int i = blockIdx.x * blockDim.x + threadIdx.x;
    if (i >= n) return;
    float ux = fminf(iU[i], vraw[i]);
    float lx = fmaxf(iL[i], vraw[n + i]);
    float uy = spu_f(ux), ly = spu_f(lx);
    float new_ub = fmaxf(uy, ly);
    float sj = (uy - ly) / (ux - lx);
    float ij = uy - sj * ux;
    bool right = lx > 0.f;
    bool left = ux <= 0.f;
    bool crossing = (!left) && (!right);
    float mid = 0.5f * (ux + lx);
    float sp = 2.f * mid, ip = -mid * mid - 0.5f;
    float sm = sigmoidf_(mid);
    float ssm = -sm * (1.f - sm);
    float ism = -sm - ssm * mid;
    float new_lb = crossing ? -0.5f : fminf(uy, ly);
    float spu_s = 2.f * ux, ipu = -ux * ux - 0.5f;
    float limit = spu_s * lx + ipu;
    float clm = (fabsf(lx) > ux) ? 1.f : 0.f;
    float clp = sigmoidf_((clm - 0.5f) * 2.f * SIG_SCALE_C) * (ly - limit) + limit;
    bool ptm = clp < -0.5f;
    float D = 4.f * lx * lx - 4.f * clp - 2.f;
    float x2 = (2.f * lx + sqrtf(fmaxf(D, 0.f))) * 0.5f;
    float spt = 2.f * x2, ipt = -x2 * x2 - 0.5f;
    float sjn = (clp + 0.5f) / lx;
    float ijn = -0.5f;
    float s_cl = ptm ? spt : sjn;
    float i_cl = ptm ? ipt : ijn;
    float sl = sigmoidf_(lx);
    float ssl = -sl * (1.f - sl);
    float isl = -sl - ssl * lx;
    float stv = ssl * ux + isl - uy;
    float Lb = lx, Rb = 0.f;
    #pragma unroll
    for (int t = 0; t < 10; ++t) {
        float mm = 0.5f * (Lb + Rb);
        float smm = sigmoidf_(mm);
        float sms = -smm * (1.f - smm);
        float smi = -smm - sms * mm;
        bool mask = (sms * ux + smi - uy) > 0.f;
        Lb = mask ? mm : Lb;
        Rb = mask ? Rb : mm;
    }
    float scp = sigmoidf_(-SIG_SCALE_C) * (Lb - lx) + lx;
    float sc = sigmoidf_(scp);
    float ssc = -sc * (1.f - sc);
    float isc = -sc - ssc * scp;
    bool up = stv > 0.f;
    float s_cu = up ? ssc : sj;
    float i_cu = up ? isc : ij;
    float usv, uiv, lsv, liv;
    if (right)      { usv = sj;   uiv = ij;   lsv = sp;   liv = ip;   }
    else if (left)  { usv = ssm;  uiv = ism;  lsv = sj;   liv = ij;   }
    else            { usv = s_cu; uiv = i_cu; lsv = s_cl; liv = i_cl; }
    us[i] = usv; ui[i] = uiv; ls[i] = lsv; li[i] = liv;
    float vu = vraw[(usv >= 0.f) ? i : n + i];
    float vl = vraw[(lsv >= 0.f) ? n + i : i];
    pU[i] = fminf(new_ub, usv * vu + uiv);
    pL[i] = fmaxf(new_lb, lsv * vl + liv);
}

// ---------------- bf16 producers ----------------

// transpose + convert + swizzle: W (K x N real, ldw) fp32 -> Wt swizzled (Npad x K)
__global__ __launch_bounds__(256) void k_wT(
        const float* __restrict__ W, int N, int ldw,
        bf16_t* __restrict__ Wt) {
    __shared__ bf16_t t[64][72];
    int k0 = blockIdx.x * 64, n0 = blockIdx.y * 64;
    int tid = threadIdx.x;
    int r = tid >> 2;
    int c0 = (tid & 3) * 16;
    const float* Wr = W + (size_t)(k0 + r) * ldw;
    #pragma unroll
    for (int c = 0; c < 16; ++c) {
        int gn = n0 + c0 + c;
        float vv = (gn < N) ? Wr[gn] : 0.f;
        t[c0 + c][r] = (bf16_t)vv;
    }
    __syncthreads();
    #pragma unroll
    for (int p = 0; p < 2; ++p) {
        int c = tid + p * 256;
        int lr = c & 63, lq = c >> 6;
        bf16x8 v;
        #pragma unroll
        for (int u = 0; u < 8; ++u) v[u] = t[lr][lq * 8 + u];
        *(bf16x8*)(Wt + swz(n0 + lr, k0 + lq * 8, KTILES)) = v;
    }
}

// prep (fused interval-affine)
__global__ __launch_bounds__(256) void k_prep16(
        const float* __restrict__ W, const float* __restrict__ b, int n,
        const float* __restrict__ cus, const float* __restrict__ cui,
        const float* __restrict__ cls, const float* __restrict__ cli,
        const float* __restrict__ bvec,
        const float* __restrict__ U, const float* __restrict__ L,
        bf16_t* __restrict__ Ab, float* __restrict__ av,
        float* __restrict__ iU, float* __restrict__ iL) {
    int rt = blockIdx.x;
    int tid = threadIdx.x, lane = tid & 63, wid = tid >> 6;
    int mrow = lane & 15, q = lane >> 4;
    int r = rt * 16 + mrow;
    bool act = r < 2 * n;
    bool isU = r < n;
    int i = act ? (isU ? r : r - n) : 0;
    float gate = act ? 1.f : 0.f;
    const float* Wr = W + (size_t)i * 2048;
    const float* ps = isU ? cus : cls;
    const float* ns = isU ? cls : cus;
    const float* yi = isU ? cui : cli;
    const float* zi = isU ? cli : cui;
    const float* hi = isU ? U : L;
    const float* lo = isU ? L : U;
    float a = 0.f, a2 = 0.f;
    bf16_t* Abase = Ab + ((size_t)rt * KTILES) * 512 + lane * 8;
    for (int kt = wid; kt < KTILES; kt += 4) {
        int k0 = kt * 32 + q * 8;
        bf16x8 ov;
        #pragma unroll
        for (int h = 0; h < 2; ++h) {
            int kb = k0 + 4 * h;
            f32x4 wv = *(const f32x4*)(Wr + kb);
            f32x4 p0 = *(const f32x4*)(ps + kb);
            f32x4 q0 = *(const f32x4*)(ns + kb);
            f32x4 y0 = *(const f32x4*)(yi + kb);
            f32x4 z0 = *(const f32x4*)(zi + kb);
            f32x4 c0 = *(const f32x4*)(bvec + kb);
            f32x4 h0 = *(const f32x4*)(hi + kb);
            f32x4 l0 = *(const f32x4*)(lo + kb);
            #pragma unroll
            for (int u = 0; u < 4; ++u) {
                float w = gate * wv[u];
                float pos = fmaxf(w, 0.f), neg = fminf(w, 0.f);
                float mx = pos * p0[u] + neg * q0[u];
                ov[4 * h + u] = (bf16_t)mx;
                a += pos * y0[u] + neg * z0[u] + mx * c0[u];
                a2 += pos * h0[u] + neg * l0[u];   // interval dot
            }
        }
        *(bf16x8*)(Abase + (size_t)kt * 512) = ov;
    }
    a += __shfl_xor(a, 16, 64);  a += __shfl_xor(a, 32, 64);
    a2 += __shfl_xor(a2, 16, 64); a2 += __shfl_xor(a2, 32, 64);
    __shared__ float sh[2][4][16];
    if (lane < 16) { sh[0][wid][lane] = a; sh[1][wid][lane] = a2; }
    __syncthreads();
    if (tid < 16) {
        int r2 = rt * 16 + tid;
        float ta = sh[0][0][tid] + sh[0][1][tid] + sh[0][2][tid] + sh[0][3][tid];
        float tb = sh[1][0][tid] + sh[1][1][tid] + sh[1][2][tid] + sh[1][3][tid];
        if (r2 < 2 * n) {
            bool isU2 = r2 < n;
            int i2 = isU2 ? r2 : r2 - n;
            av[r2] = ta + b[i2];
            if (isU2) iU[i2] = tb + b[i2];
            else      iL[i2] = tb + b[i2];
        } else {
            av[r2] = 0.f;
        }
    }
}

// colmix (layer-4 small-M chains): bf16 split slabs -> swizzled bf16 Ab
__global__ __launch_bounds__(256) void k_colmix16(
        const bf16_t* __restrict__ Cb, int ldc, int splits, size_t sstride, int n,
        int tpb,
        const float* __restrict__ cus, const float* __restrict__ cui,
        const float* __restrict__ cls, const float* __restrict__ cli,
        const float* __restrict__ bvec,
        bf16_t* __restrict__ Ab, float* __restrict__ av) {
    int rt = blockIdx.x;
    int kt0 = blockIdx.y * tpb;
    int tid = threadIdx.x, lane = tid & 63, wid = tid >> 6;
    int mrow = lane & 15, q = lane >> 4;
    int r = rt * 16 + mrow;
    bool isU = r < n;
    const bf16_t* Cr = Cb + (size_t)r * ldc;
    const float* ps = isU ? cus : cls;
    const float* ns = isU ? cls : cus;
    const float* yi = isU ? cui : cli;
    const float* zi = isU ? cli : cui;
    float a = 0.f;
    bf16_t* Abase = Ab + ((size_t)rt * KTILES) * 512 + lane * 8;
    for (int kt = kt0 + wid; kt < kt0 + tpb; kt += 4) {
        int k0 = kt * 32 + q * 8;
        float wsum[8] = {0.f, 0.f, 0.f, 0.f, 0.f, 0.f, 0.f, 0.f};
        for (int s = 0; s < splits; ++s) {
            bf16x8 v = *(const bf16x8*)(Cr + s * sstride + k0);
            #pragma unroll
            for (int u = 0; u < 8; ++u) wsum[u] += (float)v[u];
        }
        f32x4 p0 = *(const f32x4*)(ps + k0), p1 = *(const f32x4*)(ps + k0 + 4);
        f32x4 q0 = *(const f32x4*)(ns + k0), q1 = *(const f32x4*)(ns + k0 + 4);
        f32x4 y0 = *(const f32x4*)(yi + k0), y1 = *(const f32x4*)(yi + k0 + 4);
        f32x4 z0 = *(const f32x4*)(zi + k0), z1 = *(const f32x4*)(zi + k0 + 4);
        f32x4 c0 = *(const f32x4*)(bvec + k0), c1 = *(const f32x4*)(bvec + k0 + 4);
        bf16x8 ov;
        #pragma unroll
        for (int u = 0; u < 4; ++u) {
            float w = wsum[u];
            float pos = fmaxf(w, 0.f), neg = fminf(w, 0.f);
            float mx = pos * p0[u] + neg * q0[u];
            ov[u] = (bf16_t)mx;
            a += pos * y0[u] + neg * z0[u] + mx * c0[u];
        }
        #pragma unroll
        for (int u = 0; u < 4; ++u) {
            float w = wsum[4 + u];
            float pos = fmaxf(w, 0.f), neg = fminf(w, 0.f);
            float mx = pos * p1[u] + neg * q1[u];
            ov[4 + u] = (bf16_t)mx;
            a += pos * y1[u] + neg * z1[u] + mx * c1[u];
        }
        *(bf16x8*)(Abase + (size_t)kt * 512) = ov;
    }
    a += __shfl_xor(a, 16, 64);
    a += __shfl_xor(a, 32, 64);
    __shared__ float sh[4][16];
    if (lane < 16) sh[wid][lane] = a;
    __syncthreads();
    if (tid < 16) {
        float tot = sh[0][tid] + sh[1][tid] + sh[2][tid] + sh[3][tid];
        atomicAdd(&av[rt * 16 + tid], tot);
    }
}

// final c0 step (layer-4 only)
__global__ __launch_bounds__(256) void k_reduce16(
        const bf16_t* __restrict__ Cb, int ldc, int m, int n,
        int splits, size_t sstride,
        const float* __restrict__ av,
        const float* __restrict__ ubn, const float* __restrict__ lbn,
        const float* __restrict__ iU, const float* __restrict__ iL,
        float* __restrict__ vraw,
        float* __restrict__ bU, float* __restrict__ bL) {
    int r = (blockIdx.x << 2) + (threadIdx.x >> 6);
    if (r >= 2 * n) return;
    int lane = threadIdx.x & 63;
    bool isU = r < n;
    int i = isU ? r : r - n;
    const bf16_t* Cr = Cb + (size_t)r * ldc;
    const float* p = isU ? ubn : lbn;
    const float* q = isU ? lbn : ubn;
    int nch = m >> 3;   // m % 8 == 0
    float a = 0.f;
    for (int c = lane; c < nch; c += 64) {
        float wsum[8] = {0.f, 0.f, 0.f, 0.f, 0.f, 0.f, 0.f, 0.f};
        for (int s = 0; s < splits; ++s) {
            bf16x8 v = *(const bf16x8*)(Cr + s * sstride + c * 8);
            #pragma unroll
            for (int u = 0; u < 8; ++u) wsum[u] += (float)v[u];
        }
        f32x4 p0 = *(const f32x4*)(p + c * 8), p1 = *(const f32x4*)(p + c * 8 + 4);
        f32x4 q0 = *(const f32x4*)(q + c * 8), q1 = *(const f32x4*)(q + c * 8 + 4);
        #pragma unroll
        for (int u = 0; u < 4; ++u) {
            a += fmaxf(wsum[u], 0.f) * p0[u] + fminf(wsum[u], 0.f) * q0[u];
            a += fmaxf(wsum[4 + u], 0.f) * p1[u] + fminf(wsum[4 + u], 0.f) * q1[u];
        }
    }
    a = wave_sum(a);
    if (lane == 0) {
        float v = a + av[r];
        vraw[r] = v;
        if (isU) bU[i] = fminf(iU[i], v);
        else     bL[i] = fmaxf(iL[i], v);
    }
}

__global__ void k_final_min(const float* __restrict__ l, int n, float* __restrict__ out) {
    float v = 3.4e38f;
    for (int j = threadIdx.x; j < n; j += 64) v = fminf(v, l[j]);
    #pragma unroll
    for (int o = 32; o > 0; o >>= 1) v = fminf(v, __shfl_down(v, o, 64));
    if (threadIdx.x == 0) out[0] = v;
}

// ---------------- bf16 MFMA GEMM, BK=64 (layer-4, split-K, slab output) ------
__global__ __launch_bounds__(256) void k_gemm16(
        const bf16_t* __restrict__ A, const bf16_t* __restrict__ Bt,
        bf16_t* __restrict__ C, int ldc, size_t sstride, int nk) {
    __shared__ __align__(16) bf16_t As[8192];
    __shared__ __align__(16) bf16_t Bs[8192];
    int tid = threadIdx.x, lane = tid & 63, w = tid >> 6;
    int wm = w & 1, wn = w >> 1;
    int tr0 = blockIdx.y * 8, tc0 = blockIdx.x * 8;
    int kt0 = blockIdx.z * nk * 2;

    const bf16_t* a0 = A + (((size_t)(tr0 + w)     * KTILES + kt0) << 9) + lane * 8;
    const bf16_t* a1 = A + (((size_t)(tr0 + w + 4) * KTILES + kt0) << 9) + lane * 8;
    const bf16_t* b0 = Bt + (((size_t)(tc0 + w)     * KTILES + kt0) << 9) + lane * 8;
    const bf16_t* b1 = Bt + (((size_t)(tc0 + w + 4) * KTILES + kt0) << 9) + lane * 8;
    bf16_t* lA0 = &As[w * 1024];
    bf16_t* lA1 = &As[(w + 4) * 1024];
    bf16_t* lB0 = &Bs[w * 1024];
    bf16_t* lB1 = &Bs[(w + 4) * 1024];

    f32x4 acc[4][4];
    #pragma unroll
    for (int i = 0; i < 4; ++i)
        #pragma unroll
        for (int j = 0; j < 4; ++j) acc[i][j] = (f32x4){0.f, 0.f, 0.f, 0.f};

    for (int kk = 0; kk < nk; ++kk) {
        size_t go = (size_t)kk * 1024;
        g2l16(a0 + go, lA0);       g2l16(a0 + go + 512, lA0 + 512);
        g2l16(a1 + go, lA1);       g2l16(a1 + go + 512, lA1 + 512);
        g2l16(b0 + go, lB0);       g2l16(b0 + go + 512, lB0 + 512);
        g2l16(b1 + go, lB1);       g2l16(b1 + go + 512, lB1 + 512);
        __syncthreads();
        #pragma unroll
        for (int h = 0; h < 2; ++h) {
            bf16x8 af[4], bfr[4];
            #pragma unroll
            for (int i = 0; i < 4; ++i)
                af[i] = *(const bf16x8*)(&As[(wm * 4 + i) * 1024 + h * 512 + lane * 8]);
            #pragma unroll
            for (int j = 0; j < 4; ++j)
                bfr[j] = *(const bf16x8*)(&Bs[(wn * 4 + j) * 1024 + h * 512 + lane * 8]);
            #pragma unroll
            for (int i = 0; i < 4; ++i)
                #pragma unroll
                for (int j = 0; j < 4; ++j)
                    acc[i][j] = mfma16(bfr[j], af[i], acc[i][j]);   // swapped -> D^T
        }
        __syncthreads();
    }
    bf16_t* Cz = C + (size_t)blockIdx.z * sstride;
    int orow = lane & 15, ocol = (lane >> 4) * 4;
    size_t row0 = (size_t)blockIdx.y * 128;
    size_t col0 = (size_t)blockIdx.x * 128;
    #pragma unroll
    for (int i = 0; i < 4; ++i) {
        size_t gr = row0 + wm * 64 + i * 16 + orow;
        #pragma unroll
        for (int j = 0; j < 4; ++j) {
            size_t gc = col0 + wn * 64 + j * 16 + ocol;
            bf16x4 v;
            #pragma unroll
            for (int rg = 0; rg < 4; ++rg) v[rg] = (bf16_t)acc[i][j][rg];
            *(bf16x4*)(Cz + gr * (size_t)ldc + gc) = v;
        }
    }
}

// GEMM + fused colmix epilogue (splits=1, M=2n rows, N=2048 cols).
// blockIdx.x = M-tile (consecutive blocks share the B weight tile for XCD-L2).
__global__ __launch_bounds__(256) void k_gemm16_mix(
        const bf16_t* __restrict__ A, const bf16_t* __restrict__ Bt, int n,
        const float* __restrict__ cus, const float* __restrict__ cui,
        const float* __restrict__ cls, const float* __restrict__ cli,
        const float* __restrict__ bvec,
        bf16_t* __restrict__ Ab2, float* __restrict__ av, int nk) {
    __shared__ __align__(16) bf16_t As[8192];
    __shared__ __align__(16) bf16_t Bs[8192];
    __shared__ float asum[2][128];
    int tid = threadIdx.x, lane = tid & 63, w = tid >> 6;
    int wm = w & 1, wn = w >> 1;
    int tr0 = blockIdx.x * 8, tc0 = blockIdx.y * 8;

    const bf16_t* a0 = A + (((size_t)(tr0 + w)     * KTILES) << 9) + lane * 8;
    const bf16_t* a1 = A + (((size_t)(tr0 + w + 4) * KTILES) << 9) + lane * 8;
    const bf16_t* b0 = Bt + (((size_t)(tc0 + w)     * KTILES) << 9) + lane * 8;
    const bf16_t* b1 = Bt + (((size_t)(tc0 + w + 4) * KTILES) << 9) + lane * 8;
    bf16_t* lA0 = &As[w * 1024];
    bf16_t* lA1 = &As[(w + 4) * 1024];
    bf16_t* lB0 = &Bs[w * 1024];
    bf16_t* lB1 = &Bs[(w + 4) * 1024];

    f32x4 acc[4][4];
    #pragma unroll
    for (int i = 0; i < 4; ++i)
        #pragma unroll
        for (int j = 0; j < 4; ++j) acc[i][j] = (f32x4){0.f, 0.f, 0.f, 0.f};

    for (int kk = 0; kk < nk; ++kk) {
        size_t go = (size_t)kk * 1024;
        g2l16(a0 + go, lA0);       g2l16(a0 + go + 512, lA0 + 512);
        g2l16(a1 + go, lA1);       g2l16(a1 + go + 512, lA1 + 512);
        g2l16(b0 + go, lB0);       g2l16(b0 + go + 512, lB0 + 512);
        g2l16(b1 + go, lB1);       g2l16(b1 + go + 512, lB1 + 512);
        __syncthreads();
        #pragma unroll
        for (int h = 0; h < 2; ++h) {
            bf16x8 af[4], bfr[4];
            #pragma unroll
            for (int i = 0; i < 4; ++i)
                af[i] = *(const bf16x8*)(&As[(wm * 4 + i) * 1024 + h * 512 + lane * 8]);
            #pragma unroll
            for (int j = 0; j < 4; ++j)
                bfr[j] = *(const bf16x8*)(&Bs[(wn * 4 + j) * 1024 + h * 512 + lane * 8]);
            #pragma unroll
            for (int i = 0; i < 4; ++i)
                #pragma unroll
                for (int j = 0; j < 4; ++j)
                    acc[i][j] = mfma16(bfr[j], af[i], acc[i][j]);
        }
        __syncthreads();
    }
    // ---- fused colmix epilogue ----
    size_t row0 = (size_t)blockIdx.x * 128;
    size_t col0 = (size_t)blockIdx.y * 128;
    bool isU = (int)row0 < n;            // row0 multiple of 128, n multiple of 128
    const float* ps = isU ? cus : cls;
    const float* ns = isU ? cls : cus;
    const float* yi = isU ? cui : cli;
    const float* zi = isU ? cli : cui;
    int orow = lane & 15, ocol = (lane >> 4) * 4;
    #pragma unroll
    for (int i = 0; i < 4; ++i) {
        int gr = (int)row0 + wm * 64 + i * 16 + orow;
        float ra = 0.f;
        #pragma unroll
        for (int j = 0; j < 4; ++j) {
            int gc = (int)col0 + wn * 64 + j * 16 + ocol;
            f32x4 p0 = *(const f32x4*)(ps + gc);
            f32x4 q0 = *(const f32x4*)(ns + gc);
            f32x4 y0 = *(const f32x4*)(yi + gc);
            f32x4 z0 = *(const f32x4*)(zi + gc);
            f32x4 c0 = *(const f32x4*)(bvec + gc);
            bf16x4 ov;
            #pragma unroll
            for (int rg = 0; rg < 4; ++rg) {
                float v = acc[i][j][rg];
                float pos = fmaxf(v, 0.f), neg = fminf(v, 0.f);
                float mx = pos * p0[rg] + neg * q0[rg];
                ov[rg] = (bf16_t)mx;
                ra += pos * y0[rg] + neg * z0[rg] + mx * c0[rg];
            }
            *(bf16x4*)(Ab2 + swz(gr, gc, KTILES)) = ov;
        }
        ra += __shfl_xor(ra, 16, 64);
        ra += __shfl_xor(ra, 32, 64);
        if (lane < 16) asum[wn][wm * 64 + i * 16 + lane] = ra;
    }
    __syncthreads();
    if (tid < 128) atomicAdd(&av[row0 + tid], asum[0][tid] + asum[1][tid]);
}

// GEMM + fused final c0-reduce epilogue (splits=1, N = 896 padded).
// Row partial = sign-split(C row) . (ubn/lbn); atomicAdd onto av (pre-set to
// intercept by prep16) -> av becomes vraw. blockIdx.x = M-tile.
__global__ __launch_bounds__(256) void k_gemm16_red(
        const bf16_t* __restrict__ A, const bf16_t* __restrict__ Bt, int n,
        const float* __restrict__ ubn, const float* __restrict__ lbn,
        float* __restrict__ av, int nk) {
    __shared__ __align__(16) bf16_t As[8192];
    __shared__ __align__(16) bf16_t Bs[8192];
    __shared__ float asum[2][128];
    int tid = threadIdx.x, lane = tid & 63, w = tid >> 6;
    int wm = w & 1, wn = w >> 1;
    int tr0 = blockIdx.x * 8, tc0 = blockIdx.y * 8;

    const bf16_t* a0 = A + (((size_t)(tr0 + w)     * KTILES) << 9) + lane * 8;
    const bf16_t* a1 = A + (((size_t)(tr0 + w + 4) * KTILES) << 9) + lane * 8;
    const bf16_t* b0 = Bt + (((size_t)(tc0 + w)     * KTILES) << 9) + lane * 8;
    const bf16_t* b1 = Bt + (((size_t)(tc0 + w + 4) * KTILES) << 9) + lane * 8;
    bf16_t* lA0 = &As[w * 1024];
    bf16_t* lA1 = &As[(w + 4) * 1024];
    bf16_t* lB0 = &Bs[w * 1024];
    bf16_t* lB1 = &Bs[(w + 4) * 1024];

    f32x4 acc[4][4];
    #pragma unroll
    for (int i = 0; i < 4; ++i)
        #pragma unroll
        for (int j = 0; j < 4; ++j) acc[i][j] = (f32x4){0.f, 0.f, 0.f, 0.f};

    for (int kk = 0; kk < nk; ++kk) {
        size_t go = (size_t)kk * 1024;
        g2l16(a0 + go, lA0);       g2l16(a0 + go + 512, lA0 + 512);
        g2l16(a1 + go, lA1);       g2l16(a1 + go + 512, lA1 + 512);
        g2l16(b0 + go, lB0);       g2l16(b0 + go + 512, lB0 + 512);
        g2l16(b1 + go, lB1);       g2l16(b1 + go + 512, lB1 + 512);
        __syncthreads();
        #pragma unroll
        for (int h = 0; h < 2; ++h) {
            bf16x8 af[4], bfr[4];
            #pragma unroll
            for (int i = 0; i < 4; ++i)
                af[i] = *(const bf16x8*)(&As[(wm * 4 + i) * 1024 + h * 512 + lane * 8]);
            #pragma unroll
            for (int j = 0; j < 4; ++j)
                bfr[j] = *(const bf16x8*)(&Bs[(wn * 4 + j) * 1024 + h * 512 + lane * 8]);
            #pragma unroll
            for (int i = 0; i < 4; ++i)
                #pragma unroll
                for (int j = 0; j < 4; ++j)
                    acc[i][j] = mfma16(bfr[j], af[i], acc[i][j]);
        }
        __syncthreads();
    }
    // ---- fused c0-reduce epilogue ----
    size_t row0 = (size_t)blockIdx.x * 128;
    size_t col0 = (size_t)blockIdx.y * 128;
    bool isU = (int)row0 < n;
    const float* p = isU ? ubn : lbn;
    const float* q = isU ? lbn : ubn;
    int ocol = (lane >> 4) * 4;
    #pragma unroll
    for (int i = 0; i < 4; ++i) {
        float ra = 0.f;
        #pragma unroll
        for (int j = 0; j < 4; ++j) {
            int gc = (int)col0 + wn * 64 + j * 16 + ocol;
            f32x4 p0 = *(const f32x4*)(p + gc);
            f32x4 q0 = *(const f32x4*)(q + gc);
            #pragma unroll
            for (int rg = 0; rg < 4; ++rg) {
                float v = acc[i][j][rg];
                ra += fmaxf(v, 0.f) * p0[rg] + fminf(v, 0.f) * q0[rg];
            }
        }
        ra += __shfl_xor(ra, 16, 64);
        ra += __shfl_xor(ra, 32, 64);
        if (lane < 16) asum[wn][wm * 64 + i * 16 + lane] = ra;
    }
    __syncthreads();
    if (tid < 128) atomicAdd(&av[row0 + tid], asum[0][tid] + asum[1][tid]);
}

// ---------------- host launch ----------------

extern "C" void kernel_launch(void* const* d_in, const int* in_sizes, int n_in,
                              void* d_out, int out_size, void* d_ws, size_t ws_size,
                              hipStream_t stream) {
    (void)in_sizes; (void)n_in; (void)out_size; (void)ws_size;
    const float* x   = (const float*)d_in[0];
    const float* eps = (const float*)d_in[1];
    const float* W1  = (const float*)d_in[2];
    const float* B1  = (const float*)d_in[3];
    const float* W2  = (const float*)d_in[4];
    const float* B2  = (const float*)d_in[5];
    const float* W3  = (const float*)d_in[6];
    const float* B3  = (const float*)d_in[7];
    const float* W4  = (const float*)d_in[8];
    const float* B4  = (const float*)d_in[9];
    float* out = (float*)d_out;

    const int H = 2048, DIN = 784, DOUT = 10;
    const int NP1 = 896;           // DIN padded to x128
    const int MP4 = 128;           // layer-4 row pad

    float* ws = (float*)d_ws;
    size_t off = 0;
    auto alloc = [&](size_t nf) -> float* {
        float* p = ws + off;
        off += (nf + 3) & ~(size_t)3;
        return p;
    };
    float* ubn = alloc(NP1);
    float* lbn = alloc(NP1);
    float* vraw1 = alloc(2 * H);
    float* us1 = alloc(H); float* ui1 = alloc(H); float* ls1 = alloc(H); float* li1 = alloc(H);
    float* pU1 = alloc(H); float* pL1 = alloc(H);
    float* iU2 = alloc(H); float* iL2 = alloc(H);
    float* us2 = alloc(H); float* ui2 = alloc(H); float* ls2 = alloc(H); float* li2 = alloc(H);
    float* pU2 = alloc(H); float* pL2 = alloc(H);
    float* iU3 = alloc(H); float* iL3 = alloc(H);
    float* us3 = alloc(H); float* ui3 = alloc(H); float* ls3 = alloc(H); float* li3 = alloc(H);
    float* pU3 = alloc(H); float* pL3 = alloc(H);
    float* iU4 = alloc(32); float* iL4 = alloc(32);
    float* vraw4 = alloc(64);
    float* bU4 = alloc(32); float* bL4 = alloc(32);
    float* av  = alloc(2 * H);
    bf16_t* Ab  = (bf16_t*)alloc((size_t)2 * H * H / 2);       // 4096 x 2048 bf16 swz
    bf16_t* Ab2 = (bf16_t*)alloc((size_t)2 * H * H / 2);       // second operand buffer
    bf16_t* W1t = (bf16_t*)alloc((size_t)NP1 * H / 2);
    bf16_t* W2t = (bf16_t*)alloc((size_t)H * H / 2);
    bf16_t* W3t = (bf16_t*)alloc((size_t)H * H / 2);
    bf16_t* Cs  = (bf16_t*)alloc((size_t)16 * MP4 * H / 2);    // L4 split-16 slabs (bf16)

    dim3 blk(256);

    // weight transpose/convert/swizzle
    k_wT<<<dim3(H / 64, NP1 / 64), blk, 0, stream>>>(W1, DIN, DIN, W1t);
    k_wT<<<dim3(H / 64, H / 64), blk, 0, stream>>>(W2, H, H, W2t);
    k_wT<<<dim3(H / 64, H / 64), blk, 0, stream>>>(W3, H, H, W3t);

    k_input_bounds<<<dim3((NP1 + 255) / 256), blk, 0, stream>>>(x, eps, DIN, NP1, ubn, lbn);

    size_t ss4H = (size_t)MP4 * H;          // layer-4 N=H slab
    size_t ss4N = (size_t)MP4 * NP1;        // layer-4 N=NP1 slab

    // ======== Layer 1 ========
    k_interval_affine<<<dim3(H / 4), blk, 0, stream>>>(W1, B1, ubn, lbn, DIN, H,
                                                       vraw1, vraw1 + H);
    k_spu2<<<dim3(H / 256), blk, 0, stream>>>(vraw1, vraw1 + H, vraw1, H,
        us1, ui1, ls1, li1, pU1, pL1);

    // ======== Layer 2 ========
    k_prep16<<<dim3(2 * H / 16), blk, 0, stream>>>(W2, B2, H,
        us1, ui1, ls1, li1, B1, pU1, pL1, Ab, av, iU2, iL2);
    k_gemm16_red<<<dim3(2 * H / 128, NP1 / 128), blk, 0, stream>>>(Ab, W1t, H,
        ubn, lbn, av, KTILES / 2);
    k_spu2<<<dim3(H / 256), blk, 0, stream>>>(iU2, iL2, av, H,
        us2, ui2, ls2, li2, pU2, pL2);

    // ======== Layer 3 ========
    k_prep16<<<dim3(2 * H / 16), blk, 0, stream>>>(W3, B3, H,
        us2, ui2, ls2, li2, B2, pU2, pL2, Ab, av, iU3, iL3);
    k_gemm16_mix<<<dim3(2 * H / 128, H / 128), blk, 0, stream>>>(Ab, W2t, H,
        us1, ui1, ls1, li1, B1, Ab2, av, KTILES / 2);
    k_gemm16_red<<<dim3(2 * H / 128, NP1 / 128), blk, 0, stream>>>(Ab2, W1t, H,
        ubn, lbn, av, KTILES / 2);
    k_spu2<<<dim3(H / 256), blk, 0, stream>>>(iU3, iL3, av, H,
        us3, ui3, ls3, li3, pU3, pL3);

    // ======== Layer 4 (M = 20 padded to 128, split-K 16, colmix k-split 8) ========
    k_prep16<<<dim3(MP4 / 16), blk, 0, stream>>>(W4, B4, DOUT,
        us3, ui3, ls3, li3, B3, pU3, pL3, Ab, av, iU4, iL4);
    k_gemm16<<<dim3(H / 128, MP4 / 128, 16), blk, 0, stream>>>(Ab, W3t, Cs, H, ss4H, 2);
    k_colmix16<<<dim3(MP4 / 16, 8), blk, 0, stream>>>(Cs, H, 16, ss4H, DOUT, KTILES / 8,
        us2, ui2, ls2, li2, B2, Ab2, av);
    k_gemm16<<<dim3(H / 128, MP4 / 128, 16), blk, 0, stream>>>(Ab2, W2t, Cs, H, ss4H, 2);
    k_colmix16<<<dim3(MP4 / 16, 8), blk, 0, stream>>>(Cs, H, 16, ss4H, DOUT, KTILES / 8,
        us1, ui1, ls1, li1, B1, Ab, av);
    k_gemm16<<<dim3(NP1 / 128, MP4 / 128, 16), blk, 0, stream>>>(Ab, W1t, Cs, NP1, ss4N, 2);
    k_reduce16<<<dim3((2 * DOUT + 3) / 4), blk, 0, stream>>>(Cs, NP1, DIN, DOUT, 16, ss4N,
        av, ubn, lbn, iU4, iL4, vraw4, bU4, bL4);

    k_final_min<<<dim3(1), dim3(64), 0, stream>>>(bL4, DOUT, out);
}